// Round 1
// baseline (1163.286 us; speedup 1.0000x reference)
//
#include <hip/hip_runtime.h>
#include <math.h>

#define DIMC 128
#define LSEQ 12288
#define NB 2
#define BLR 24576   // NB*LSEQ
#define EPSV 1e-5f

__device__ __forceinline__ float sigf(float x){ return 1.f/(1.f+__expf(-x)); }
__device__ __forceinline__ float softplusf(float x){ return fmaxf(x,0.f) + log1pf(__expf(-fabsf(x))); }

// ---------------------------------------------------------------- lam = sigmoid(sum(lambda_q))
__global__ void k_lam(const float* __restrict__ lq, float* __restrict__ lam){
    int lane = threadIdx.x;                    // block = 64
    float v = lq[lane] + lq[lane+64];
    for (int m = 32; m; m >>= 1) v += __shfl_xor(v, m);
    if (lane == 0) *lam = 1.f/(1.f+__expf(-v));
}

// ---------------------------------------------------------------- W_all[inst][144][128]
// rows 0..127  : Wc[j][k] = sum_r dt_w[j][r]*xp_w[r][k]   (dt path folded)
// rows 128..135: xp_w rows 8..15   (Bc)
// rows 136..143: xp_w rows 16..23  (Cc)
__global__ void k_wall(const float* __restrict__ dtw, const float* __restrict__ xpw,
                       float* __restrict__ wall){
    int inst = blockIdx.x, j = blockIdx.y, k = threadIdx.x;  // grid (4,144), block 128
    const float* xp = xpw + (size_t)inst*24*128;
    float v;
    if (j < 128){
        const float* dw = dtw + (size_t)inst*128*8 + (size_t)j*8;
        v = 0.f;
        #pragma unroll
        for (int r = 0; r < 8; r++) v += dw[r]*xp[r*128 + k];
    } else {
        v = xp[(8 + (j-128))*128 + k];
    }
    wall[((size_t)inst*144 + j)*128 + k] = v;
}

// ---------------------------------------------------------------- LN1 row stats (mean, rsqrt(var+eps))
__global__ __launch_bounds__(256) void k_stats(const float* __restrict__ x, float* __restrict__ stats){
    int row  = blockIdx.x*4 + (threadIdx.x >> 6);   // 4 waves/block, grid 6144
    int lane = threadIdx.x & 63;
    int b = row / LSEQ, l = row % LSEQ;
    const float* xp = x + (size_t)b*DIMC*LSEQ + l;
    float v0 = xp[(size_t)lane*LSEQ];
    float v1 = xp[(size_t)(lane+64)*LSEQ];
    float s = v0+v1, s2 = v0*v0 + v1*v1;
    for (int m = 32; m; m >>= 1){ s += __shfl_xor(s, m); s2 += __shfl_xor(s2, m); }
    if (lane == 0){
        float mu = s*(1.f/128.f);
        float var = s2*(1.f/128.f) - mu*mu;
        stats[row*2]   = mu;
        stats[row*2+1] = rsqrtf(var + EPSV);
    }
}

// ---------------------------------------------------------------- in_proj GEMM (LN fused into A-load)
// C[bl][j] = sum_c LN(x)[bl][c] * wi[j][c],  j in 0..511 (m-major; 0..127 xh0,128..255 z0,256..383 xh1,384..511 z1)
__global__ __launch_bounds__(256) void k_inproj(const float* __restrict__ x, const float* __restrict__ stats,
    const float* __restrict__ w1, const float* __restrict__ b1,
    const float* __restrict__ wi, float* __restrict__ xz)
{
    __shared__ float As[16][68];
    __shared__ float Bs[16][68];
    const int row0 = blockIdx.x * 64;          // grid.x = 384
    const int j0   = blockIdx.y * 64;          // grid.y = 8
    const int b  = row0 / LSEQ;
    const int l0 = row0 % LSEQ;                // 64 | LSEQ so tile stays in one b
    const int tid = threadIdx.x;
    const int tn = tid & 15, tm = tid >> 4;    // n = tn*4 (coalesced store), m = tm*4
    const int mA = tid & 63;
    const float mu = stats[(row0+mA)*2];
    const float rs = stats[(row0+mA)*2+1];
    float acc[4][4] = {};
    for (int k0 = 0; k0 < 128; k0 += 16){
        #pragma unroll
        for (int p = 0; p < 4; p++){
            int ck = (tid >> 6) + p*4;
            int c  = k0 + ck;
            float xv = x[(size_t)b*DIMC*LSEQ + (size_t)c*LSEQ + l0 + mA];
            As[ck][mA] = (xv - mu)*rs*w1[c] + b1[c];
        }
        #pragma unroll
        for (int p = 0; p < 4; p++){
            int ck = tid & 15;
            int n  = (tid >> 4) + p*16;
            Bs[ck][n] = wi[(size_t)(j0+n)*128 + k0 + ck];
        }
        __syncthreads();
        #pragma unroll
        for (int k = 0; k < 16; k++){
            float4 a = *(const float4*)&As[k][tm*4];
            float4 q = *(const float4*)&Bs[k][tn*4];
            float av[4] = {a.x,a.y,a.z,a.w};
            float bv[4] = {q.x,q.y,q.z,q.w};
            #pragma unroll
            for (int i = 0; i < 4; i++)
                #pragma unroll
                for (int j = 0; j < 4; j++)
                    acc[i][j] += av[i]*bv[j];
        }
        __syncthreads();
    }
    #pragma unroll
    for (int i = 0; i < 4; i++){
        float4 v = make_float4(acc[i][0], acc[i][1], acc[i][2], acc[i][3]);
        *(float4*)&xz[(size_t)(row0 + tm*4 + i)*512 + j0 + tn*4] = v;
    }
}

// ---------------------------------------------------------------- causal dwconv + silu, transposed store
// xc[inst][b][dim][L] in DIRECTION-LOCAL order (bwd sequence stored reversed)
__global__ __launch_bounds__(256) void k_conv(const float* __restrict__ xz, const float* __restrict__ cw,
    const float* __restrict__ cb, float* __restrict__ xc)
{
    __shared__ float tile[67][129];
    const int bid = blockIdx.x;                // 4*2*192
    const int lt = bid % 192;
    const int bb = (bid/192) % NB;
    const int inst = bid / (192*NB);
    const int m = inst >> 1, d = inst & 1;
    const int l0 = lt * 64;
    const int tid = threadIdx.x;
    const int cc = tid & 127, r2 = tid >> 7;
    for (int p = 0; p < 34; p++){
        int r = p*2 + r2;
        if (r < 67){
            int ld = l0 - 3 + r;               // direction-local index
            float v = 0.f;
            if (ld >= 0){
                int lo = d ? (LSEQ-1-ld) : ld; // original position
                v = xz[((size_t)(bb*LSEQ + lo))*512 + m*256 + cc];
            }
            tile[r][cc] = v;
        }
    }
    __syncthreads();
    const int li = tid & 63, dg = tid >> 6;
    for (int p = 0; p < 32; p++){
        int dim = p*4 + dg;
        const float* w = cw + ((size_t)inst*DIMC + dim)*4;
        float w0 = w[0], w1v = w[1], w2 = w[2], w3 = w[3];
        float v = cb[inst*DIMC + dim]
                + w0*tile[li  ][dim] + w1v*tile[li+1][dim]
                + w2*tile[li+2][dim] + w3*tile[li+3][dim];
        v = v * sigf(v);                        // silu
        xc[(((size_t)inst*NB + bb)*DIMC + dim)*LSEQ + l0 + li] = v;
    }
}

// ---------------------------------------------------------------- z transpose: zT[m][b][dim][L] (original order)
__global__ __launch_bounds__(256) void k_ztrans(const float* __restrict__ xz, float* __restrict__ zT){
    __shared__ float t[64][129];
    const int bid = blockIdx.x;                // 2*2*192
    const int lt = bid % 192;
    const int bb = (bid/192) % NB;
    const int m = bid / (192*NB);
    const int l0 = lt*64;
    const int tid = threadIdx.x;
    const int cc = tid & 127, r2 = tid >> 7;
    for (int p = 0; p < 32; p++){
        int r = p*2 + r2;
        t[r][cc] = xz[((size_t)(bb*LSEQ + l0 + r))*512 + m*256 + 128 + cc];
    }
    __syncthreads();
    const int li = tid & 63, cg = tid >> 6;
    for (int p = 0; p < 32; p++){
        int c = p*4 + cg;
        zT[(((size_t)m*NB + bb)*DIMC + c)*LSEQ + l0 + li] = t[li][c];
    }
}

// ---------------------------------------------------------------- x_proj GEMM: [L x 144 x 128] per (inst,b)
// epilogue: cols 0..127 -> softplus(+dt_b) -> dtT[inst][b][dim][L]; cols 128..143 -> bc[inst][b][l][16]
__global__ __launch_bounds__(256) void k_xproj(const float* __restrict__ xc, const float* __restrict__ wall,
    const float* __restrict__ dtb, float* __restrict__ dtT, float* __restrict__ bcb)
{
    __shared__ float As[32][68];
    __shared__ float Bs[32][145];
    const int mt = blockIdx.x;                 // 0..191
    const int ib = blockIdx.y;                 // inst*NB + bb
    const int inst = ib >> 1;
    const int l0 = mt * 64;
    const int tid = threadIdx.x;
    const int tx = tid & 15, ty = tid >> 4;    // m = tx*4, n = ty*9
    const size_t abase = ((size_t)ib * DIMC) * LSEQ;
    float acc[4][9] = {};
    for (int k0 = 0; k0 < 128; k0 += 32){
        int mi = tid & 63, ckg = tid >> 6;
        #pragma unroll
        for (int p = 0; p < 8; p++){
            int ck = p*4 + ckg;
            As[ck][mi] = xc[abase + (size_t)(k0+ck)*LSEQ + l0 + mi];
        }
        int ckb = tid & 31, ng = tid >> 5;
        #pragma unroll
        for (int p = 0; p < 18; p++){
            int n = p*8 + ng;
            Bs[ckb][n] = wall[((size_t)inst*144 + n)*128 + k0 + ckb];
        }
        __syncthreads();
        #pragma unroll
        for (int k = 0; k < 32; k++){
            float4 a = *(const float4*)&As[k][tx*4];
            float av[4] = {a.x,a.y,a.z,a.w};
            #pragma unroll
            for (int jj = 0; jj < 9; jj++){
                float bv = Bs[k][ty*9+jj];
                acc[0][jj] += av[0]*bv; acc[1][jj] += av[1]*bv;
                acc[2][jj] += av[2]*bv; acc[3][jj] += av[3]*bv;
            }
        }
        __syncthreads();
    }
    #pragma unroll
    for (int jj = 0; jj < 9; jj++){
        int n = ty*9 + jj;
        if (n < 128){
            float bias = dtb[inst*DIMC + n];
            float4 v = make_float4(softplusf(acc[0][jj]+bias), softplusf(acc[1][jj]+bias),
                                   softplusf(acc[2][jj]+bias), softplusf(acc[3][jj]+bias));
            *(float4*)&dtT[abase + (size_t)n*LSEQ + l0 + tx*4] = v;
        } else {
            int q = n - 128;
            #pragma unroll
            for (int i = 0; i < 4; i++)
                bcb[((size_t)ib*LSEQ + l0 + tx*4 + i)*16 + q] = acc[i][jj];
        }
    }
}

// ---------------------------------------------------------------- selective scan (block per inst,b,dim)
// writes y*silu(z) IN PLACE over dtT (local order); safe: each thread overwrites only consumed positions
__global__ __launch_bounds__(256) void k_scan(float* __restrict__ dtT, const float* __restrict__ xc,
    const float* __restrict__ bcb, const float* __restrict__ zT,
    const float* __restrict__ alog, const float* __restrict__ dvec)
{
    __shared__ float sc[256*17];
    const int bid = blockIdx.x;                // 1024
    const int dim = bid & 127;
    const int ib  = bid >> 7;                  // inst*NB + bb
    const int inst = ib >> 1, bb = ib & 1;
    const int m = inst >> 1, d = inst & 1;
    const int t = threadIdx.x;
    float* dtrow = dtT + ((size_t)ib*DIMC + dim)*LSEQ;
    const float* urow  = xc + ((size_t)ib*DIMC + dim)*LSEQ;
    const float* bcrow = bcb + (size_t)ib*LSEQ*16;
    const float* zrow  = zT + (((size_t)m*NB + bb)*DIMC + dim)*LSEQ;
    float Av[8];
    #pragma unroll
    for (int n = 0; n < 8; n++) Av[n] = -__expf(alog[((size_t)inst*DIMC + dim)*8 + n]);
    const float Dv = dvec[inst*DIMC + dim];
    const int l0 = t * 48;
    float Ac[8], Bc_[8];
    #pragma unroll
    for (int n = 0; n < 8; n++){ Ac[n] = 1.f; Bc_[n] = 0.f; }
    for (int i = 0; i < 48; i++){
        int l = l0 + i;
        float dt = dtrow[l];
        float u  = urow[l];
        const float* bp = bcrow + (size_t)l*16;
        float4 b0 = *(const float4*)(bp);
        float4 b1 = *(const float4*)(bp+4);
        float bv[8] = {b0.x,b0.y,b0.z,b0.w,b1.x,b1.y,b1.z,b1.w};
        float du = dt*u;
        #pragma unroll
        for (int n = 0; n < 8; n++){
            float a = __expf(dt*Av[n]);
            Bc_[n] = a*Bc_[n] + du*bv[n];
            Ac[n] *= a;
        }
    }
    #pragma unroll
    for (int n = 0; n < 8; n++){ sc[t*17+n] = Ac[n]; sc[t*17+8+n] = Bc_[n]; }
    for (int off = 1; off < 256; off <<= 1){
        __syncthreads();
        float pa[8], pb[8];
        const bool has = (t >= off);
        if (has){
            #pragma unroll
            for (int n = 0; n < 8; n++){ pa[n] = sc[(t-off)*17+n]; pb[n] = sc[(t-off)*17+8+n]; }
        }
        __syncthreads();
        if (has){
            #pragma unroll
            for (int n = 0; n < 8; n++){
                Bc_[n] = Ac[n]*pb[n] + Bc_[n];   // (prev ∘ cur): B = A_cur*B_prev + B_cur
                Ac[n] *= pa[n];
                sc[t*17+n] = Ac[n]; sc[t*17+8+n] = Bc_[n];
            }
        }
    }
    __syncthreads();
    float h[8];
    #pragma unroll
    for (int n = 0; n < 8; n++) h[n] = (t == 0) ? 0.f : sc[(t-1)*17+8+n];
    for (int i = 0; i < 48; i++){
        int l = l0 + i;
        float dt = dtrow[l];
        float u  = urow[l];
        const float* bp = bcrow + (size_t)l*16;
        float4 b0 = *(const float4*)(bp);
        float4 b1 = *(const float4*)(bp+4);
        float4 c0 = *(const float4*)(bp+8);
        float4 c1 = *(const float4*)(bp+12);
        float bv[8] = {b0.x,b0.y,b0.z,b0.w,b1.x,b1.y,b1.z,b1.w};
        float cv[8] = {c0.x,c0.y,c0.z,c0.w,c1.x,c1.y,c1.z,c1.w};
        float du = dt*u;
        float y = 0.f;
        #pragma unroll
        for (int n = 0; n < 8; n++){
            float a = __expf(dt*Av[n]);
            h[n] = a*h[n] + du*bv[n];
            y += h[n]*cv[n];
        }
        y += u*Dv;
        int lo = d ? (LSEQ-1-l) : l;
        float zv = zrow[lo];
        y *= zv * sigf(zv);
        dtrow[l] = y;                           // local order; k_final reverses bwd reads
    }
}

// ---------------------------------------------------------------- out_proj + (y1 - lam*y2) + LN + add x + LN + transpose store
__global__ __launch_bounds__(256) void k_final(const float* __restrict__ y, const float* __restrict__ ow,
    const float* __restrict__ x, const float* __restrict__ lamp,
    const float* __restrict__ sw, const float* __restrict__ sb,
    const float* __restrict__ n2w, const float* __restrict__ n2b,
    float* __restrict__ outp)
{
    __shared__ float sm[10752];                 // compute: As 2*32*36=2304, Bs 2*32*132=8448
    float* Asm = sm;
    float* Bsm = sm + 2304;
    const int bb = blockIdx.y;
    const int l0 = blockIdx.x * 32;            // grid.x = 384
    const int tid = threadIdx.x;
    const float lam = *lamp;
    const int tx = tid & 7, ty = tid >> 3;     // l = tx*4, j = ty*4
    float acc[2][4][4] = {};
    for (int k0 = 0; k0 < 128; k0 += 32){
        int li = tid & 31, g = tid >> 5;
        #pragma unroll
        for (int p = 0; p < 8; p++){
            int idx = p*8 + g;                 // 0..63 -> (m, ck)
            int mm = idx >> 5, ck = idx & 31;
            float vf = y[(((size_t)(mm*2+0)*NB + bb)*DIMC + k0+ck)*LSEQ + l0 + li];
            float vb = y[(((size_t)(mm*2+1)*NB + bb)*DIMC + k0+ck)*LSEQ + (LSEQ-1-l0-li)];
            Asm[(mm*32 + ck)*36 + li] = vf + vb;
        }
        int ckb = tid & 31, g2 = tid >> 5;
        #pragma unroll
        for (int p = 0; p < 32; p++){
            int idx = p*8 + g2;                // 0..255 -> (m, j)
            int mm = idx >> 7, j = idx & 127;
            Bsm[(mm*32 + ckb)*132 + j] = ow[((size_t)mm*DIMC + j)*DIMC + k0 + ckb];
        }
        __syncthreads();
        #pragma unroll
        for (int k = 0; k < 32; k++){
            float4 a0 = *(const float4*)&Asm[(0*32+k)*36 + tx*4];
            float4 a1 = *(const float4*)&Asm[(1*32+k)*36 + tx*4];
            float4 q0 = *(const float4*)&Bsm[(0*32+k)*132 + ty*4];
            float4 q1 = *(const float4*)&Bsm[(1*32+k)*132 + ty*4];
            float a0v[4] = {a0.x,a0.y,a0.z,a0.w};
            float a1v[4] = {a1.x,a1.y,a1.z,a1.w};
            float b0v[4] = {q0.x,q0.y,q0.z,q0.w};
            float b1v[4] = {q1.x,q1.y,q1.z,q1.w};
            #pragma unroll
            for (int i = 0; i < 4; i++)
                #pragma unroll
                for (int j = 0; j < 4; j++){
                    acc[0][i][j] += a0v[i]*b0v[j];
                    acc[1][i][j] += a1v[i]*b1v[j];
                }
        }
        __syncthreads();                       // also protects the aliased epilogue regions
    }
    // epilogue (aliases sm): yt[32][129], xt[32][129], red1[264], red2[264], stt[64]
    float* yt   = sm;
    float* xt   = sm + 4128;
    float* red1 = sm + 8256;
    float* red2 = sm + 8520;
    float* stt  = sm + 8784;
    #pragma unroll
    for (int i = 0; i < 4; i++)
        #pragma unroll
        for (int jj = 0; jj < 4; jj++)
            yt[(tx*4+i)*129 + ty*4+jj] = acc[0][i][jj] - lam*acc[1][i][jj];
    {
        int li = tid & 31, cg = tid >> 5;
        #pragma unroll
        for (int p = 0; p < 16; p++){
            int c = p*8 + cg;
            xt[li*129 + c] = x[(size_t)bb*DIMC*LSEQ + (size_t)c*LSEQ + l0 + li];
        }
    }
    __syncthreads();
    const int r = tid & 31, g = tid >> 5;      // lanes contiguous in r -> coalesced final store
    float s = 0.f, s2 = 0.f;
    #pragma unroll
    for (int k = 0; k < 16; k++){ float v = yt[r*129 + g*16 + k]; s += v; s2 += v*v; }
    red1[g*33 + r] = s; red2[g*33 + r] = s2;
    __syncthreads();
    if (tid < 32){
        float ss = 0.f, ss2 = 0.f;
        #pragma unroll
        for (int gg = 0; gg < 8; gg++){ ss += red1[gg*33 + tid]; ss2 += red2[gg*33 + tid]; }
        float mu = ss*(1.f/128.f);
        float var = ss2*(1.f/128.f) - mu*mu;
        stt[tid*2] = mu; stt[tid*2+1] = rsqrtf(var + EPSV);
    }
    __syncthreads();
    float mu1 = stt[r*2], rs1 = stt[r*2+1];
    s = 0.f; s2 = 0.f;
    #pragma unroll
    for (int k = 0; k < 16; k++){
        int c = g*16 + k;
        float v = (yt[r*129+c] - mu1)*rs1*sw[c] + sb[c] + xt[r*129+c];
        yt[r*129+c] = v;
        s += v; s2 += v*v;
    }
    __syncthreads();
    red1[g*33 + r] = s; red2[g*33 + r] = s2;
    __syncthreads();
    if (tid < 32){
        float ss = 0.f, ss2 = 0.f;
        #pragma unroll
        for (int gg = 0; gg < 8; gg++){ ss += red1[gg*33 + tid]; ss2 += red2[gg*33 + tid]; }
        float mu = ss*(1.f/128.f);
        float var = ss2*(1.f/128.f) - mu*mu;
        stt[tid*2] = mu; stt[tid*2+1] = rsqrtf(var + EPSV);
    }
    __syncthreads();
    float mu2 = stt[r*2], rs2 = stt[r*2+1];
    #pragma unroll
    for (int k = 0; k < 16; k++){
        int c = g*16 + k;
        float o = (yt[r*129+c] - mu2)*rs2*n2w[c] + n2b[c];
        outp[(size_t)bb*DIMC*LSEQ + (size_t)c*LSEQ + l0 + r] = o;
    }
}

// ----------------------------------------------------------------
extern "C" void kernel_launch(void* const* d_in, const int* in_sizes, int n_in,
                              void* d_out, int out_size, void* d_ws, size_t ws_size,
                              hipStream_t stream)
{
    const float* x    = (const float*)d_in[0];
    const float* n1w  = (const float*)d_in[1];
    const float* n1b  = (const float*)d_in[2];
    const float* n2w  = (const float*)d_in[3];
    const float* n2b  = (const float*)d_in[4];
    const float* slw  = (const float*)d_in[5];
    const float* slb  = (const float*)d_in[6];
    const float* lq   = (const float*)d_in[7];
    const float* wi   = (const float*)d_in[8];
    const float* cw   = (const float*)d_in[9];
    const float* cb   = (const float*)d_in[10];
    const float* xpw  = (const float*)d_in[11];
    const float* dtw  = (const float*)d_in[12];
    const float* dtb  = (const float*)d_in[13];
    const float* alog = (const float*)d_in[14];
    const float* dvec = (const float*)d_in[15];
    const float* ow   = (const float*)d_in[16];

    float* ws    = (float*)d_ws;
    float* stats = ws;                         //    49152
    float* xz    = stats + 49152;              // 12582912  (reused as dtT after conv/ztrans consume it)
    float* xc    = xz + 12582912;              // 12582912
    float* zT    = xc + 12582912;              //  6291456
    float* bcb   = zT + 6291456;               //  1572864
    float* wall  = bcb + 1572864;              //    73728
    float* lam   = wall + 73728;               //        1
    float* dtT   = xz;                         // alias: xz is dead after k_conv/k_ztrans

    k_lam   <<<1, 64, 0, stream>>>(lq, lam);
    k_wall  <<<dim3(4,144), 128, 0, stream>>>(dtw, xpw, wall);
    k_stats <<<BLR/4, 256, 0, stream>>>(x, stats);
    k_inproj<<<dim3(BLR/64, 8), 256, 0, stream>>>(x, stats, n1w, n1b, wi, xz);
    k_conv  <<<4*NB*(LSEQ/64), 256, 0, stream>>>(xz, cw, cb, xc);
    k_ztrans<<<2*NB*(LSEQ/64), 256, 0, stream>>>(xz, zT);
    k_xproj <<<dim3(LSEQ/64, 4*NB), 256, 0, stream>>>(xc, wall, dtb, dtT, bcb);
    k_scan  <<<4*NB*DIMC, 256, 0, stream>>>(dtT, xc, bcb, zT, alog, dvec);
    k_final <<<dim3(LSEQ/32, NB), 256, 0, stream>>>(dtT, ow, x, lam, slw, slb, n2w, n2b, (float*)d_out);
}

// Round 2
// 427.853 us; speedup vs baseline: 2.7189x; 2.7189x over previous
//
#include <hip/hip_runtime.h>
#include <math.h>

#define DIMC 128
#define LSEQ 12288
#define NB 2
#define BLR 24576   // NB*LSEQ
#define EPSV 1e-5f
#define NCH 96      // scan chunks per row
#define LC 128      // chunk length (NCH*LC = LSEQ)

__device__ __forceinline__ float sigf(float x){ return 1.f/(1.f+__expf(-x)); }
__device__ __forceinline__ float softplusf(float x){ return fmaxf(x,0.f) + log1pf(__expf(-fabsf(x))); }
__device__ __forceinline__ float bf2f(unsigned short u){
    union { unsigned int i; float f; } v; v.i = ((unsigned int)u) << 16; return v.f;
}
__device__ __forceinline__ unsigned short f2bf(float f){
    union { float f; unsigned int i; } v; v.f = f;
    unsigned int b = v.i + 0x7FFFu + ((v.i >> 16) & 1u);
    return (unsigned short)(b >> 16);
}

// ---------------------------------------------------------------- lam = sigmoid(sum(lambda_q))
__global__ void k_lam(const float* __restrict__ lq, float* __restrict__ lam){
    int lane = threadIdx.x;                    // block = 64
    float v = lq[lane] + lq[lane+64];
    for (int m = 32; m; m >>= 1) v += __shfl_xor(v, m);
    if (lane == 0) *lam = 1.f/(1.f+__expf(-v));
}

// ---------------------------------------------------------------- W_all[inst][144][128]
__global__ void k_wall(const float* __restrict__ dtw, const float* __restrict__ xpw,
                       float* __restrict__ wall){
    int inst = blockIdx.x, j = blockIdx.y, k = threadIdx.x;  // grid (4,144), block 128
    const float* xp = xpw + (size_t)inst*24*128;
    float v;
    if (j < 128){
        const float* dw = dtw + (size_t)inst*128*8 + (size_t)j*8;
        v = 0.f;
        #pragma unroll
        for (int r = 0; r < 8; r++) v += dw[r]*xp[r*128 + k];
    } else {
        v = xp[(8 + (j-128))*128 + k];
    }
    wall[((size_t)inst*144 + j)*128 + k] = v;
}

// ---------------------------------------------------------------- LN1 row stats
__global__ __launch_bounds__(256) void k_stats(const float* __restrict__ x, float* __restrict__ stats){
    int row  = blockIdx.x*4 + (threadIdx.x >> 6);
    int lane = threadIdx.x & 63;
    int b = row / LSEQ, l = row % LSEQ;
    const float* xp = x + (size_t)b*DIMC*LSEQ + l;
    float v0 = xp[(size_t)lane*LSEQ];
    float v1 = xp[(size_t)(lane+64)*LSEQ];
    float s = v0+v1, s2 = v0*v0 + v1*v1;
    for (int m = 32; m; m >>= 1){ s += __shfl_xor(s, m); s2 += __shfl_xor(s2, m); }
    if (lane == 0){
        float mu = s*(1.f/128.f);
        float var = s2*(1.f/128.f) - mu*mu;
        stats[row*2]   = mu;
        stats[row*2+1] = rsqrtf(var + EPSV);
    }
}

// ---------------------------------------------------------------- in_proj GEMM (LN fused), bf16 out
__global__ __launch_bounds__(256) void k_inproj(const float* __restrict__ x, const float* __restrict__ stats,
    const float* __restrict__ w1, const float* __restrict__ b1,
    const float* __restrict__ wi, unsigned short* __restrict__ xz)
{
    __shared__ float As[16][68];
    __shared__ float Bs[16][68];
    const int row0 = blockIdx.x * 64;          // grid.x = 384
    const int j0   = blockIdx.y * 64;          // grid.y = 8
    const int b  = row0 / LSEQ;
    const int l0 = row0 % LSEQ;
    const int tid = threadIdx.x;
    const int tn = tid & 15, tm = tid >> 4;
    const int mA = tid & 63;
    const float mu = stats[(row0+mA)*2];
    const float rs = stats[(row0+mA)*2+1];
    float acc[4][4] = {};
    for (int k0 = 0; k0 < 128; k0 += 16){
        #pragma unroll
        for (int p = 0; p < 4; p++){
            int ck = (tid >> 6) + p*4;
            int c  = k0 + ck;
            float xv = x[(size_t)b*DIMC*LSEQ + (size_t)c*LSEQ + l0 + mA];
            As[ck][mA] = (xv - mu)*rs*w1[c] + b1[c];
        }
        #pragma unroll
        for (int p = 0; p < 4; p++){
            int ck = tid & 15;
            int n  = (tid >> 4) + p*16;
            Bs[ck][n] = wi[(size_t)(j0+n)*128 + k0 + ck];
        }
        __syncthreads();
        #pragma unroll
        for (int k = 0; k < 16; k++){
            float4 a = *(const float4*)&As[k][tm*4];
            float4 q = *(const float4*)&Bs[k][tn*4];
            float av[4] = {a.x,a.y,a.z,a.w};
            float bv[4] = {q.x,q.y,q.z,q.w};
            #pragma unroll
            for (int i = 0; i < 4; i++)
                #pragma unroll
                for (int j = 0; j < 4; j++)
                    acc[i][j] += av[i]*bv[j];
        }
        __syncthreads();
    }
    #pragma unroll
    for (int i = 0; i < 4; i++){
        ushort4 v;
        v.x = f2bf(acc[i][0]); v.y = f2bf(acc[i][1]);
        v.z = f2bf(acc[i][2]); v.w = f2bf(acc[i][3]);
        *(ushort4*)&xz[(size_t)(row0 + tm*4 + i)*512 + j0 + tn*4] = v;
    }
}

// ---------------------------------------------------------------- conv (both directions) + silu
// reads xz xh-cols [l][dim] rows, writes xc[inst][b][l][dim] bf16 (ORIGINAL l order;
// d=1 holds the anticausal conv: xc_d1(l) = sum_k w[k]*xh(l+3-k))
__global__ __launch_bounds__(256) void k_conv(const unsigned short* __restrict__ xz,
    const float* __restrict__ cw, const float* __restrict__ cb, unsigned short* __restrict__ xc)
{
    __shared__ unsigned short tile[70][144];
    const int bid = blockIdx.x;                // grid = 2*2*192
    const int lt = bid % 192;
    const int bb = (bid/192) % NB;
    const int m  = bid / (192*NB);
    const int l0 = lt * 64;
    const int tid = threadIdx.x;
    for (int idx = tid; idx < 70*16; idx += 256){
        int r = idx >> 4, cq = idx & 15;
        int l = l0 - 3 + r;
        uint4 v = make_uint4(0,0,0,0);
        if (l >= 0 && l < LSEQ)
            v = *(const uint4*)&xz[((size_t)(bb*LSEQ + l))*512 + m*256 + cq*8];
        *(uint4*)&tile[r][cq*8] = v;
    }
    __syncthreads();
    const int dimi = tid & 127, lg = tid >> 7;
    float w0a[4], w1a[4];
    #pragma unroll
    for (int k = 0; k < 4; k++){
        w0a[k] = cw[((size_t)(m*2+0)*DIMC + dimi)*4 + k];
        w1a[k] = cw[((size_t)(m*2+1)*DIMC + dimi)*4 + k];
    }
    const float b0 = cb[(m*2+0)*DIMC + dimi];
    const float b1v = cb[(m*2+1)*DIMC + dimi];
    for (int p = 0; p < 32; p++){
        int li = p*2 + lg;
        float t0 = bf2f(tile[li  ][dimi]);
        float t1 = bf2f(tile[li+1][dimi]);
        float t2 = bf2f(tile[li+2][dimi]);
        float t3 = bf2f(tile[li+3][dimi]);
        float t4 = bf2f(tile[li+4][dimi]);
        float t5 = bf2f(tile[li+5][dimi]);
        float t6 = bf2f(tile[li+6][dimi]);
        float v0 = b0  + w0a[0]*t0 + w0a[1]*t1 + w0a[2]*t2 + w0a[3]*t3;
        float v1 = b1v + w1a[3]*t3 + w1a[2]*t4 + w1a[1]*t5 + w1a[0]*t6;
        v0 = v0 * sigf(v0);
        v1 = v1 * sigf(v1);
        xc[(((size_t)(m*2+0)*NB + bb)*LSEQ + l0 + li)*DIMC + dimi] = f2bf(v0);
        xc[(((size_t)(m*2+1)*NB + bb)*LSEQ + l0 + li)*DIMC + dimi] = f2bf(v1);
    }
}

// ---------------------------------------------------------------- x_proj GEMM: [64l x 144n x 128k] per (ib)
// A = xc bf16 rows; out: n<128 -> softplus(+dtb) -> dt bf16 [ib][l][dim]; n>=128 -> bcb fp32 [ib][l][16]
__global__ __launch_bounds__(256) void k_xproj(const unsigned short* __restrict__ xc,
    const float* __restrict__ wall, const float* __restrict__ dtb,
    unsigned short* __restrict__ dt, float* __restrict__ bcb)
{
    __shared__ float As[32][68];
    __shared__ float Bs[32][145];
    const int mt = blockIdx.x;                 // 0..191
    const int ib = blockIdx.y;                 // inst*NB + bb
    const int inst = ib >> 1;
    const int l0 = mt * 64;
    const int tid = threadIdx.x;
    const int tx = tid & 15, ty = tid >> 4;    // m = tx*4, n = ty*9
    const size_t abase = (size_t)ib * LSEQ * DIMC;
    float acc[4][9] = {};
    for (int k0 = 0; k0 < 128; k0 += 32){
        {
            int row = tid >> 2, cq = (tid & 3) * 8;
            uint4 v = *(const uint4*)&xc[abase + (size_t)(l0+row)*DIMC + k0 + cq];
            const unsigned short* up = (const unsigned short*)&v;
            #pragma unroll
            for (int j = 0; j < 8; j++) As[cq+j][row] = bf2f(up[j]);
        }
        int ckb = tid & 31, ng = tid >> 5;
        #pragma unroll
        for (int p = 0; p < 18; p++){
            int n = p*8 + ng;
            Bs[ckb][n] = wall[((size_t)inst*144 + n)*128 + k0 + ckb];
        }
        __syncthreads();
        #pragma unroll
        for (int k = 0; k < 32; k++){
            float4 a = *(const float4*)&As[k][tx*4];
            float av[4] = {a.x,a.y,a.z,a.w};
            #pragma unroll
            for (int jj = 0; jj < 9; jj++){
                float bv = Bs[k][ty*9+jj];
                acc[0][jj] += av[0]*bv; acc[1][jj] += av[1]*bv;
                acc[2][jj] += av[2]*bv; acc[3][jj] += av[3]*bv;
            }
        }
        __syncthreads();
    }
    #pragma unroll
    for (int jj = 0; jj < 9; jj++){
        int n = ty*9 + jj;
        if (n < 128){
            float bias = dtb[inst*DIMC + n];
            #pragma unroll
            for (int i = 0; i < 4; i++)
                dt[abase + (size_t)(l0+tx*4+i)*DIMC + n] = f2bf(softplusf(acc[i][jj]+bias));
        } else {
            int q = n - 128;
            #pragma unroll
            for (int i = 0; i < 4; i++)
                bcb[((size_t)ib*LSEQ + l0 + tx*4 + i)*16 + q] = acc[i][jj];
        }
    }
}

// ---------------------------------------------------------------- scan S1: per-chunk (A-prod, B-acc)
// block = 128 thr (one dim each); grid = 8*NCH; d=1 walks l descending (original coords)
__global__ __launch_bounds__(128) void k_scan1(const unsigned short* __restrict__ dt,
    const unsigned short* __restrict__ xc, const float* __restrict__ bcb,
    const float* __restrict__ alog, float* __restrict__ st)
{
    const int ib = blockIdx.x & 7;
    const int c  = blockIdx.x >> 3;
    const int inst = ib >> 1;
    const int d = inst & 1;
    const int tid = threadIdx.x;
    float Av[8];
    #pragma unroll
    for (int n = 0; n < 8; n++) Av[n] = -__expf(alog[((size_t)inst*DIMC + tid)*8 + n]);
    const size_t rbase = (size_t)ib*LSEQ*DIMC;
    float Ac[8], Bc[8];
    #pragma unroll
    for (int n = 0; n < 8; n++){ Ac[n] = 1.f; Bc[n] = 0.f; }
    #pragma unroll 4
    for (int s = 0; s < LC; s++){
        int j = c*LC + s;
        int l = d ? (LSEQ-1-j) : j;
        size_t ro = rbase + (size_t)l*DIMC + tid;
        float dtv = bf2f(dt[ro]);
        float uv  = bf2f(xc[ro]);
        const float* bp = bcb + ((size_t)ib*LSEQ + l)*16;
        float4 bA = *(const float4*)bp;
        float4 bB = *(const float4*)(bp+4);
        float bv[8] = {bA.x,bA.y,bA.z,bA.w,bB.x,bB.y,bB.z,bB.w};
        float du = dtv*uv;
        #pragma unroll
        for (int n = 0; n < 8; n++){
            float a = __expf(dtv*Av[n]);
            Bc[n] = a*Bc[n] + du*bv[n];
            Ac[n] *= a;
        }
    }
    float* so = st + (((size_t)ib*NCH + c)*DIMC + tid)*16;
    #pragma unroll
    for (int n = 0; n < 8; n++){ so[n] = Ac[n]; so[8+n] = Bc[n]; }
}

// ---------------------------------------------------------------- scan S2: exclusive prefix across chunks
__global__ __launch_bounds__(256) void k_scan2(const float* __restrict__ st, float* __restrict__ hst){
    int gid = blockIdx.x*256 + threadIdx.x;    // 8192 threads, grid 32
    int ib = gid >> 10;
    int r  = gid & 1023;                        // dim*8 + n
    int dim = r >> 3, n = r & 7;
    float Bp = 0.f;
    for (int c = 0; c < NCH; c++){
        size_t o = (((size_t)ib*NCH + c)*DIMC + dim)*16;
        float A = st[o+n], Bv = st[o+8+n];
        hst[(((size_t)ib*NCH + c)*DIMC + dim)*8 + n] = Bp;
        Bp = A*Bp + Bv;
    }
}

// ---------------------------------------------------------------- scan S3: replay + y = sum(h*C) + u*D, gate silu(z)
// writes y bf16 IN PLACE over dt (read-then-write, same thread, same chunk)
__global__ __launch_bounds__(128) void k_scan3(unsigned short* __restrict__ dty,
    const unsigned short* __restrict__ xc, const float* __restrict__ bcb,
    const unsigned short* __restrict__ xz, const float* __restrict__ hst,
    const float* __restrict__ alog, const float* __restrict__ dvec)
{
    const int ib = blockIdx.x & 7;
    const int c  = blockIdx.x >> 3;
    const int inst = ib >> 1, bb = ib & 1;
    const int m = inst >> 1, d = inst & 1;
    const int tid = threadIdx.x;
    float Av[8];
    #pragma unroll
    for (int n = 0; n < 8; n++) Av[n] = -__expf(alog[((size_t)inst*DIMC + tid)*8 + n]);
    const float Dv = dvec[inst*DIMC + tid];
    float h[8];
    #pragma unroll
    for (int n = 0; n < 8; n++) h[n] = hst[(((size_t)ib*NCH + c)*DIMC + tid)*8 + n];
    const size_t rbase = (size_t)ib*LSEQ*DIMC;
    const size_t zbase = (size_t)bb*LSEQ*512 + m*256 + 128;
    #pragma unroll 2
    for (int s = 0; s < LC; s++){
        int j = c*LC + s;
        int l = d ? (LSEQ-1-j) : j;
        size_t ro = rbase + (size_t)l*DIMC + tid;
        float dtv = bf2f(dty[ro]);
        float uv  = bf2f(xc[ro]);
        const float* bp = bcb + ((size_t)ib*LSEQ + l)*16;
        float4 bA = *(const float4*)bp;
        float4 bB = *(const float4*)(bp+4);
        float4 cA = *(const float4*)(bp+8);
        float4 cB = *(const float4*)(bp+12);
        float bv[8] = {bA.x,bA.y,bA.z,bA.w,bB.x,bB.y,bB.z,bB.w};
        float cv[8] = {cA.x,cA.y,cA.z,cA.w,cB.x,cB.y,cB.z,cB.w};
        float du = dtv*uv;
        float y = uv*Dv;
        #pragma unroll
        for (int n = 0; n < 8; n++){
            float a = __expf(dtv*Av[n]);
            h[n] = a*h[n] + du*bv[n];
            y += h[n]*cv[n];
        }
        float zv = bf2f(xz[zbase + (size_t)l*512 + tid]);
        y *= zv * sigf(zv);
        dty[ro] = f2bf(y);
    }
}

// ---------------------------------------------------------------- out_proj + diff + LN + add x + LN + transposed store
__global__ __launch_bounds__(256) void k_final(const unsigned short* __restrict__ y, const float* __restrict__ ow,
    const float* __restrict__ x, const float* __restrict__ lamp,
    const float* __restrict__ sw, const float* __restrict__ sb,
    const float* __restrict__ n2w, const float* __restrict__ n2b,
    float* __restrict__ outp)
{
    __shared__ float sm[10752];
    float* Asm = sm;
    float* Bsm = sm + 2304;
    const int bb = blockIdx.y;
    const int l0 = blockIdx.x * 32;            // grid.x = 384
    const int tid = threadIdx.x;
    const float lam = *lamp;
    const int tx = tid & 7, ty = tid >> 3;
    float acc[2][4][4] = {};
    for (int k0 = 0; k0 < 128; k0 += 32){
        {
            int row = tid >> 3;                // 0..31 (l)
            int cq = (tid & 7) * 4;            // 0..28 (k)
            #pragma unroll
            for (int mm = 0; mm < 2; mm++){
                uint2 vf = *(const uint2*)&y[(((size_t)(mm*2+0)*NB + bb)*LSEQ + l0 + row)*DIMC + k0 + cq];
                uint2 vb = *(const uint2*)&y[(((size_t)(mm*2+1)*NB + bb)*LSEQ + l0 + row)*DIMC + k0 + cq];
                const unsigned short* uf = (const unsigned short*)&vf;
                const unsigned short* ub = (const unsigned short*)&vb;
                #pragma unroll
                for (int j = 0; j < 4; j++)
                    Asm[(mm*32 + cq + j)*36 + row] = bf2f(uf[j]) + bf2f(ub[j]);
            }
        }
        int ckb = tid & 31, g2 = tid >> 5;
        #pragma unroll
        for (int p = 0; p < 32; p++){
            int idx = p*8 + g2;
            int mm = idx >> 7, j = idx & 127;
            Bsm[(mm*32 + ckb)*132 + j] = ow[((size_t)mm*DIMC + j)*DIMC + k0 + ckb];
        }
        __syncthreads();
        #pragma unroll
        for (int k = 0; k < 32; k++){
            float4 a0 = *(const float4*)&Asm[(0*32+k)*36 + tx*4];
            float4 a1 = *(const float4*)&Asm[(1*32+k)*36 + tx*4];
            float4 q0 = *(const float4*)&Bsm[(0*32+k)*132 + ty*4];
            float4 q1 = *(const float4*)&Bsm[(1*32+k)*132 + ty*4];
            float a0v[4] = {a0.x,a0.y,a0.z,a0.w};
            float a1v[4] = {a1.x,a1.y,a1.z,a1.w};
            float b0v[4] = {q0.x,q0.y,q0.z,q0.w};
            float b1v[4] = {q1.x,q1.y,q1.z,q1.w};
            #pragma unroll
            for (int i = 0; i < 4; i++)
                #pragma unroll
                for (int j = 0; j < 4; j++){
                    acc[0][i][j] += a0v[i]*b0v[j];
                    acc[1][i][j] += a1v[i]*b1v[j];
                }
        }
        __syncthreads();
    }
    float* yt   = sm;
    float* xt   = sm + 4128;
    float* red1 = sm + 8256;
    float* red2 = sm + 8520;
    float* stt  = sm + 8784;
    #pragma unroll
    for (int i = 0; i < 4; i++)
        #pragma unroll
        for (int jj = 0; jj < 4; jj++)
            yt[(tx*4+i)*129 + ty*4+jj] = acc[0][i][jj] - lam*acc[1][i][jj];
    {
        int li = tid & 31, cg = tid >> 5;
        #pragma unroll
        for (int p = 0; p < 16; p++){
            int c = p*8 + cg;
            xt[li*129 + c] = x[(size_t)bb*DIMC*LSEQ + (size_t)c*LSEQ + l0 + li];
        }
    }
    __syncthreads();
    const int r = tid & 31, g = tid >> 5;
    float s = 0.f, s2 = 0.f;
    #pragma unroll
    for (int k = 0; k < 16; k++){ float v = yt[r*129 + g*16 + k]; s += v; s2 += v*v; }
    red1[g*33 + r] = s; red2[g*33 + r] = s2;
    __syncthreads();
    if (tid < 32){
        float ss = 0.f, ss2 = 0.f;
        #pragma unroll
        for (int gg = 0; gg < 8; gg++){ ss += red1[gg*33 + tid]; ss2 += red2[gg*33 + tid]; }
        float mu = ss*(1.f/128.f);
        float var = ss2*(1.f/128.f) - mu*mu;
        stt[tid*2] = mu; stt[tid*2+1] = rsqrtf(var + EPSV);
    }
    __syncthreads();
    float mu1 = stt[r*2], rs1 = stt[r*2+1];
    s = 0.f; s2 = 0.f;
    #pragma unroll
    for (int k = 0; k < 16; k++){
        int c = g*16 + k;
        float v = (yt[r*129+c] - mu1)*rs1*sw[c] + sb[c] + xt[r*129+c];
        yt[r*129+c] = v;
        s += v; s2 += v*v;
    }
    __syncthreads();
    red1[g*33 + r] = s; red2[g*33 + r] = s2;
    __syncthreads();
    if (tid < 32){
        float ss = 0.f, ss2 = 0.f;
        #pragma unroll
        for (int gg = 0; gg < 8; gg++){ ss += red1[gg*33 + tid]; ss2 += red2[gg*33 + tid]; }
        float mu = ss*(1.f/128.f);
        float var = ss2*(1.f/128.f) - mu*mu;
        stt[tid*2] = mu; stt[tid*2+1] = rsqrtf(var + EPSV);
    }
    __syncthreads();
    float mu2 = stt[r*2], rs2 = stt[r*2+1];
    #pragma unroll
    for (int k = 0; k < 16; k++){
        int c = g*16 + k;
        float o = (yt[r*129+c] - mu2)*rs2*n2w[c] + n2b[c];
        outp[(size_t)bb*DIMC*LSEQ + (size_t)c*LSEQ + l0 + r] = o;
    }
}

// ----------------------------------------------------------------
extern "C" void kernel_launch(void* const* d_in, const int* in_sizes, int n_in,
                              void* d_out, int out_size, void* d_ws, size_t ws_size,
                              hipStream_t stream)
{
    const float* x    = (const float*)d_in[0];
    const float* n1w  = (const float*)d_in[1];
    const float* n1b  = (const float*)d_in[2];
    const float* n2w  = (const float*)d_in[3];
    const float* n2b  = (const float*)d_in[4];
    const float* slw  = (const float*)d_in[5];
    const float* slb  = (const float*)d_in[6];
    const float* lq   = (const float*)d_in[7];
    const float* wi   = (const float*)d_in[8];
    const float* cw   = (const float*)d_in[9];
    const float* cb   = (const float*)d_in[10];
    const float* xpw  = (const float*)d_in[11];
    const float* dtw  = (const float*)d_in[12];
    const float* dtb  = (const float*)d_in[13];
    const float* alog = (const float*)d_in[14];
    const float* dvec = (const float*)d_in[15];
    const float* ow   = (const float*)d_in[16];

    float* ws = (float*)d_ws;
    float*          stats = ws;                               //    49152 floats
    unsigned short* xz    = (unsigned short*)(ws + 49152);    // 12582912 ushorts (6291456 f)
    unsigned short* xc    = (unsigned short*)(ws + 6340608);  // 12582912 ushorts
    unsigned short* dty   = (unsigned short*)(ws + 12632064); // 12582912 ushorts
    float*          bcb   = ws + 18923520;                    //  1572864
    float*          st1   = ws + 20496384;                    //  1572864
    float*          hst   = ws + 22069248;                    //   786432
    float*          wall  = ws + 22855680;                    //    73728
    float*          lam   = ws + 22929408;                    //        1

    k_lam   <<<1, 64, 0, stream>>>(lq, lam);
    k_wall  <<<dim3(4,144), 128, 0, stream>>>(dtw, xpw, wall);
    k_stats <<<BLR/4, 256, 0, stream>>>(x, stats);
    k_inproj<<<dim3(BLR/64, 8), 256, 0, stream>>>(x, stats, n1w, n1b, wi, xz);
    k_conv  <<<2*NB*(LSEQ/64), 256, 0, stream>>>(xz, cw, cb, xc);
    k_xproj <<<dim3(LSEQ/64, 4*NB), 256, 0, stream>>>(xc, wall, dtb, dty, bcb);
    k_scan1 <<<8*NCH, 128, 0, stream>>>(dty, xc, bcb, alog, st1);
    k_scan2 <<<32, 256, 0, stream>>>(st1, hst);
    k_scan3 <<<8*NCH, 128, 0, stream>>>(dty, xc, bcb, xz, hst, alog, dvec);
    k_final <<<dim3(LSEQ/32, NB), 256, 0, stream>>>(dty, ow, x, lam, slw, slb, n2w, n2b, (float*)d_out);
}

// Round 6
// 317.054 us; speedup vs baseline: 3.6691x; 1.3495x over previous
//
#include <hip/hip_runtime.h>
#include <math.h>

#define DIMC 128
#define LSEQ 12288
#define NB 2
#define BLR 24576   // NB*LSEQ
#define EPSV 1e-5f
#define NCH 96      // scan chunks per row
#define LC 128      // chunk length (NCH*LC = LSEQ)
#define KP 132      // LDS row pad (ushorts) for MFMA staging

typedef __bf16 bf16x8 __attribute__((ext_vector_type(8)));
typedef __attribute__((ext_vector_type(4))) float f4_t;

__device__ __forceinline__ float sigf(float x){ return 1.f/(1.f+__expf(-x)); }
__device__ __forceinline__ float softplusf(float x){ return fmaxf(x,0.f) + log1pf(__expf(-fabsf(x))); }
__device__ __forceinline__ float bf2f(unsigned short u){
    union { unsigned int i; float f; } v; v.i = ((unsigned int)u) << 16; return v.f;
}
__device__ __forceinline__ unsigned short f2bf(float f){
    union { float f; unsigned int i; } v; v.f = f;
    unsigned int b = v.i + 0x7FFFu + ((v.i >> 16) & 1u);
    return (unsigned short)(b >> 16);
}
__device__ __forceinline__ bf16x8 ld_frag8(const unsigned short* p){   // 8B-aligned LDS
    union { uint2 u[2]; bf16x8 v; } r;
    r.u[0] = *(const uint2*)(p);
    r.u[1] = *(const uint2*)(p+4);
    return r.v;
}
__device__ __forceinline__ bf16x8 ld_frag16g(const unsigned short* p){ // 16B-aligned global
    union { uint4 u; bf16x8 v; } r; r.u = *(const uint4*)p; return r.v;
}

// ---------------------------------------------------------------- lam = sigmoid(sum(lambda_q))
__global__ void k_lam(const float* __restrict__ lq, float* __restrict__ lam){
    int lane = threadIdx.x;
    float v = lq[lane] + lq[lane+64];
    for (int m = 32; m; m >>= 1) v += __shfl_xor(v, m);
    if (lane == 0) *lam = 1.f/(1.f+__expf(-v));
}

// ---------------------------------------------------------------- W_all[inst][144][128] (bf16)
__global__ void k_wall(const float* __restrict__ dtw, const float* __restrict__ xpw,
                       unsigned short* __restrict__ wallb){
    int inst = blockIdx.x, j = blockIdx.y, k = threadIdx.x;  // grid (4,144), block 128
    const float* xp = xpw + (size_t)inst*24*128;
    float v;
    if (j < 128){
        const float* dw = dtw + (size_t)inst*128*8 + (size_t)j*8;
        v = 0.f;
        #pragma unroll
        for (int r = 0; r < 8; r++) v += dw[r]*xp[r*128 + k];
    } else {
        v = xp[(8 + (j-128))*128 + k];
    }
    wallb[((size_t)inst*144 + j)*128 + k] = f2bf(v);
}

// ---------------------------------------------------------------- wi, ow -> bf16
__global__ __launch_bounds__(256) void k_prep(const float* __restrict__ wi, const float* __restrict__ ow,
    unsigned short* __restrict__ wib, unsigned short* __restrict__ owb){
    int idx = (blockIdx.x*256 + threadIdx.x)*4;   // grid 96 -> 98304 elems
    const float* src; unsigned short* dst; int off;
    if (idx < 65536){ src = wi;  dst = wib; off = idx; }
    else            { src = ow;  dst = owb; off = idx - 65536; }
    float4 v = *(const float4*)&src[off];
    ushort4 o; o.x=f2bf(v.x); o.y=f2bf(v.y); o.z=f2bf(v.z); o.w=f2bf(v.w);
    *(ushort4*)&dst[off] = o;
}

// ---------------------------------------------------------------- LN1 (stats fused) + transpose -> xn bf16 [b*l][128]
__global__ __launch_bounds__(256) void k_normT(const float* __restrict__ x,
    const float* __restrict__ w1, const float* __restrict__ b1, unsigned short* __restrict__ xn)
{
    __shared__ float t[64*129];
    __shared__ float red1[256], red2[256];
    __shared__ float stt[128];
    const int bb = blockIdx.x / 192;
    const int l0 = (blockIdx.x % 192) * 64;
    const int tid = threadIdx.x;
    const int li = tid & 63, cg = tid >> 6;
    #pragma unroll
    for (int p = 0; p < 32; p++){
        int c = p*4 + cg;
        t[li*129 + c] = x[(size_t)bb*DIMC*LSEQ + (size_t)c*LSEQ + l0 + li];
    }
    __syncthreads();
    {
        int r = tid >> 2, qg = tid & 3;
        float s = 0.f, s2 = 0.f;
        #pragma unroll
        for (int j = 0; j < 32; j++){ float v = t[r*129 + qg*32 + j]; s += v; s2 += v*v; }
        red1[qg*64 + r] = s; red2[qg*64 + r] = s2;
    }
    __syncthreads();
    if (tid < 64){
        float s = 0.f, s2 = 0.f;
        #pragma unroll
        for (int g = 0; g < 4; g++){ s += red1[g*64 + tid]; s2 += red2[g*64 + tid]; }
        float mu = s*(1.f/128.f);
        float var = s2*(1.f/128.f) - mu*mu;
        stt[tid*2] = mu; stt[tid*2+1] = rsqrtf(var + EPSV);
    }
    __syncthreads();
    const int c2 = (tid & 63)*2, lg = tid >> 6;
    #pragma unroll
    for (int p = 0; p < 16; p++){
        int l = p*4 + lg;
        float mu = stt[l*2], rs = stt[l*2+1];
        float v0 = (t[l*129 + c2    ] - mu)*rs*w1[c2    ] + b1[c2    ];
        float v1 = (t[l*129 + c2 + 1] - mu)*rs*w1[c2 + 1] + b1[c2 + 1];
        unsigned int o = (unsigned int)f2bf(v0) | ((unsigned int)f2bf(v1) << 16);
        *(unsigned int*)&xn[(size_t)(bb*LSEQ + l0 + l)*DIMC + c2] = o;
    }
}

// ---------------------------------------------------------------- in_proj MFMA: [128m x 128n x 128k] tiles
// A staged in LDS (33.8 KB); B fragments read direct from global (weights L1/L2-hot)
__global__ __launch_bounds__(256,2) void k_inproj(const unsigned short* __restrict__ xn,
    const unsigned short* __restrict__ wib, unsigned short* __restrict__ xz)
{
    __shared__ __align__(16) unsigned short As[128*KP];   // 33792 B
    const int row0 = blockIdx.x * 128;   // grid.x = 192
    const int j0   = blockIdx.y * 128;   // grid.y = 4
    const int tid = threadIdx.x;
    #pragma unroll
    for (int p = 0; p < 8; p++){
        int idx = p*256 + tid; int li = idx >> 4; int g = (idx & 15)*8;
        uint4 va = *(const uint4*)&xn[(size_t)(row0+li)*DIMC + g];
        *(uint2*)&As[li*KP + g]     = make_uint2(va.x, va.y);
        *(uint2*)&As[li*KP + g + 4] = make_uint2(va.z, va.w);
    }
    __syncthreads();
    const int lane = tid & 63, w = tid >> 6;
    const int m15 = lane & 15, q = lane >> 4;
    f4_t zf = {0.f,0.f,0.f,0.f};
    f4_t acc[2][8];
    #pragma unroll
    for (int i = 0; i < 2; i++)
        #pragma unroll
        for (int j = 0; j < 8; j++) acc[i][j] = zf;
    #pragma unroll
    for (int ks = 0; ks < 4; ks++){
        int k0 = ks*32 + q*8;
        bf16x8 a0 = ld_frag8(&As[(w*32      + m15)*KP + k0]);
        bf16x8 a1 = ld_frag8(&As[(w*32 + 16 + m15)*KP + k0]);
        #pragma unroll
        for (int nt = 0; nt < 8; nt++){
            bf16x8 b = ld_frag16g(&wib[(size_t)(j0 + nt*16 + m15)*DIMC + k0]);
            acc[0][nt] = __builtin_amdgcn_mfma_f32_16x16x32_bf16(a0, b, acc[0][nt], 0,0,0);
            acc[1][nt] = __builtin_amdgcn_mfma_f32_16x16x32_bf16(a1, b, acc[1][nt], 0,0,0);
        }
    }
    __syncthreads();
    unsigned short* ep = As;             // reuse
    #pragma unroll
    for (int mi = 0; mi < 2; mi++)
        #pragma unroll
        for (int nt = 0; nt < 8; nt++){
            int row = w*32 + mi*16 + q*4;
            int col = nt*16 + m15;
            #pragma unroll
            for (int i = 0; i < 4; i++)
                ep[(row+i)*KP + col] = f2bf(acc[mi][nt][i]);
        }
    __syncthreads();
    #pragma unroll
    for (int p = 0; p < 8; p++){
        int idx = p*256 + tid; int li = idx >> 4; int g = (idx & 15)*8;
        uint2 u0 = *(const uint2*)&ep[li*KP + g];
        uint2 u1 = *(const uint2*)&ep[li*KP + g + 4];
        uint4 o; o.x=u0.x; o.y=u0.y; o.z=u1.x; o.w=u1.y;
        *(uint4*)&xz[(size_t)(row0+li)*512 + j0 + g] = o;
    }
}

// ---------------------------------------------------------------- conv (both directions) + silu
__global__ __launch_bounds__(256) void k_conv(const unsigned short* __restrict__ xz,
    const float* __restrict__ cw, const float* __restrict__ cb, unsigned short* __restrict__ xc)
{
    __shared__ unsigned short tile[70][144];
    const int bid = blockIdx.x;                // grid = 2*2*192
    const int lt = bid % 192;
    const int bb = (bid/192) % NB;
    const int m  = bid / (192*NB);
    const int l0 = lt * 64;
    const int tid = threadIdx.x;
    for (int idx = tid; idx < 70*16; idx += 256){
        int r = idx >> 4, cq = idx & 15;
        int l = l0 - 3 + r;
        uint4 v = make_uint4(0,0,0,0);
        if (l >= 0 && l < LSEQ)
            v = *(const uint4*)&xz[((size_t)(bb*LSEQ + l))*512 + m*256 + cq*8];
        *(uint4*)&tile[r][cq*8] = v;
    }
    __syncthreads();
    const int dimi = tid & 127, lg = tid >> 7;
    float w0a[4], w1a[4];
    #pragma unroll
    for (int k = 0; k < 4; k++){
        w0a[k] = cw[((size_t)(m*2+0)*DIMC + dimi)*4 + k];
        w1a[k] = cw[((size_t)(m*2+1)*DIMC + dimi)*4 + k];
    }
    const float b0 = cb[(m*2+0)*DIMC + dimi];
    const float b1v = cb[(m*2+1)*DIMC + dimi];
    for (int p = 0; p < 32; p++){
        int li = p*2 + lg;
        float t0 = bf2f(tile[li  ][dimi]);
        float t1 = bf2f(tile[li+1][dimi]);
        float t2 = bf2f(tile[li+2][dimi]);
        float t3 = bf2f(tile[li+3][dimi]);
        float t4 = bf2f(tile[li+4][dimi]);
        float t5 = bf2f(tile[li+5][dimi]);
        float t6 = bf2f(tile[li+6][dimi]);
        float v0 = b0  + w0a[0]*t0 + w0a[1]*t1 + w0a[2]*t2 + w0a[3]*t3;
        float v1 = b1v + w1a[3]*t3 + w1a[2]*t4 + w1a[1]*t5 + w1a[0]*t6;
        v0 = v0 * sigf(v0);
        v1 = v1 * sigf(v1);
        xc[(((size_t)(m*2+0)*NB + bb)*LSEQ + l0 + li)*DIMC + dimi] = f2bf(v0);
        xc[(((size_t)(m*2+1)*NB + bb)*LSEQ + l0 + li)*DIMC + dimi] = f2bf(v1);
    }
}

// ---------------------------------------------------------------- x_proj MFMA: [128m x 144n x 128k] per ib
// A in LDS; B (wallb) direct from global; bc scratch in separate LDS region
__global__ __launch_bounds__(256,2) void k_xproj(const unsigned short* __restrict__ xc,
    const unsigned short* __restrict__ wallb, const float* __restrict__ dtb,
    unsigned short* __restrict__ dty, float* __restrict__ bcb)
{
    __shared__ __align__(16) unsigned short As[128*KP];   // 33792 B
    __shared__ __align__(16) float bq[128*17];            //  8704 B
    const int row0 = blockIdx.x * 128;   // grid.x = 96
    const int ib   = blockIdx.y;         // 0..7
    const int inst = ib >> 1;
    const int tid = threadIdx.x;
    const size_t abase = (size_t)ib * LSEQ * DIMC;
    #pragma unroll
    for (int p = 0; p < 8; p++){
        int idx = p*256 + tid; int li = idx >> 4; int g = (idx & 15)*8;
        uint4 va = *(const uint4*)&xc[abase + (size_t)(row0+li)*DIMC + g];
        *(uint2*)&As[li*KP + g]     = make_uint2(va.x, va.y);
        *(uint2*)&As[li*KP + g + 4] = make_uint2(va.z, va.w);
    }
    __syncthreads();
    const int lane = tid & 63, w = tid >> 6;
    const int m15 = lane & 15, q = lane >> 4;
    f4_t zf = {0.f,0.f,0.f,0.f};
    f4_t acc[2][9];
    #pragma unroll
    for (int i = 0; i < 2; i++)
        #pragma unroll
        for (int j = 0; j < 9; j++) acc[i][j] = zf;
    #pragma unroll
    for (int ks = 0; ks < 4; ks++){
        int k0 = ks*32 + q*8;
        bf16x8 a0 = ld_frag8(&As[(w*32      + m15)*KP + k0]);
        bf16x8 a1 = ld_frag8(&As[(w*32 + 16 + m15)*KP + k0]);
        #pragma unroll
        for (int nt = 0; nt < 9; nt++){
            bf16x8 b = ld_frag16g(&wallb[((size_t)inst*144 + nt*16 + m15)*DIMC + k0]);
            acc[0][nt] = __builtin_amdgcn_mfma_f32_16x16x32_bf16(a0, b, acc[0][nt], 0,0,0);
            acc[1][nt] = __builtin_amdgcn_mfma_f32_16x16x32_bf16(a1, b, acc[1][nt], 0,0,0);
        }
    }
    __syncthreads();
    unsigned short* ep = As;             // dt bf16 [128][KP]
    #pragma unroll
    for (int mi = 0; mi < 2; mi++){
        int row = w*32 + mi*16 + q*4;
        #pragma unroll
        for (int nt = 0; nt < 8; nt++){
            int col = nt*16 + m15;
            float bias = dtb[inst*DIMC + col];
            #pragma unroll
            for (int i = 0; i < 4; i++)
                ep[(row+i)*KP + col] = f2bf(softplusf(acc[mi][nt][i] + bias));
        }
        #pragma unroll
        for (int i = 0; i < 4; i++)
            bq[(row+i)*17 + m15] = acc[mi][8][i];
    }
    __syncthreads();
    #pragma unroll
    for (int p = 0; p < 8; p++){
        int idx = p*256 + tid; int li = idx >> 4; int g = (idx & 15)*8;
        uint2 u0 = *(const uint2*)&ep[li*KP + g];
        uint2 u1 = *(const uint2*)&ep[li*KP + g + 4];
        uint4 o; o.x=u0.x; o.y=u0.y; o.z=u1.x; o.w=u1.y;
        *(uint4*)&dty[abase + (size_t)(row0+li)*DIMC + g] = o;
    }
    #pragma unroll
    for (int p = 0; p < 2; p++){
        int idx = p*256 + tid; int li = idx >> 2; int c4 = (idx & 3)*4;
        float4 v;
        v.x = bq[li*17 + c4]; v.y = bq[li*17 + c4 + 1];
        v.z = bq[li*17 + c4 + 2]; v.w = bq[li*17 + c4 + 3];
        *(float4*)&bcb[((size_t)ib*LSEQ + row0 + li)*16 + c4] = v;
    }
}

// ---------------------------------------------------------------- scan S1
__global__ __launch_bounds__(128) void k_scan1(const unsigned short* __restrict__ dt,
    const unsigned short* __restrict__ xc, const float* __restrict__ bcb,
    const float* __restrict__ alog, float* __restrict__ st)
{
    const int ib = blockIdx.x & 7;
    const int c  = blockIdx.x >> 3;
    const int inst = ib >> 1;
    const int d = inst & 1;
    const int tid = threadIdx.x;
    float Av[8];
    #pragma unroll
    for (int n = 0; n < 8; n++) Av[n] = -__expf(alog[((size_t)inst*DIMC + tid)*8 + n]);
    const size_t rbase = (size_t)ib*LSEQ*DIMC;
    float Ac[8], Bc[8];
    #pragma unroll
    for (int n = 0; n < 8; n++){ Ac[n] = 1.f; Bc[n] = 0.f; }
    #pragma unroll 4
    for (int s = 0; s < LC; s++){
        int j = c*LC + s;
        int l = d ? (LSEQ-1-j) : j;
        size_t ro = rbase + (size_t)l*DIMC + tid;
        float dtv = bf2f(dt[ro]);
        float uv  = bf2f(xc[ro]);
        const float* bp = bcb + ((size_t)ib*LSEQ + l)*16;
        float4 bA = *(const float4*)bp;
        float4 bB = *(const float4*)(bp+4);
        float bv[8] = {bA.x,bA.y,bA.z,bA.w,bB.x,bB.y,bB.z,bB.w};
        float du = dtv*uv;
        #pragma unroll
        for (int n = 0; n < 8; n++){
            float a = __expf(dtv*Av[n]);
            Bc[n] = a*Bc[n] + du*bv[n];
            Ac[n] *= a;
        }
    }
    float* so = st + (((size_t)ib*NCH + c)*DIMC + tid)*16;
    #pragma unroll
    for (int n = 0; n < 8; n++){ so[n] = Ac[n]; so[8+n] = Bc[n]; }
}

// ---------------------------------------------------------------- scan S2
__global__ __launch_bounds__(256) void k_scan2(const float* __restrict__ st, float* __restrict__ hst){
    int gid = blockIdx.x*256 + threadIdx.x;    // 8192 threads
    int ib = gid >> 10;
    int r  = gid & 1023;
    int dim = r >> 3, n = r & 7;
    float Bp = 0.f;
    for (int c = 0; c < NCH; c++){
        size_t o = (((size_t)ib*NCH + c)*DIMC + dim)*16;
        float A = st[o+n], Bv = st[o+8+n];
        hst[(((size_t)ib*NCH + c)*DIMC + dim)*8 + n] = Bp;
        Bp = A*Bp + Bv;
    }
}

// ---------------------------------------------------------------- scan S3 (y in place over dt)
__global__ __launch_bounds__(128) void k_scan3(unsigned short* __restrict__ dty,
    const unsigned short* __restrict__ xc, const float* __restrict__ bcb,
    const unsigned short* __restrict__ xz, const float* __restrict__ hst,
    const float* __restrict__ alog, const float* __restrict__ dvec)
{
    const int ib = blockIdx.x & 7;
    const int c  = blockIdx.x >> 3;
    const int inst = ib >> 1, bb = ib & 1;
    const int m = inst >> 1, d = inst & 1;
    const int tid = threadIdx.x;
    float Av[8];
    #pragma unroll
    for (int n = 0; n < 8; n++) Av[n] = -__expf(alog[((size_t)inst*DIMC + tid)*8 + n]);
    const float Dv = dvec[inst*DIMC + tid];
    float h[8];
    #pragma unroll
    for (int n = 0; n < 8; n++) h[n] = hst[(((size_t)ib*NCH + c)*DIMC + tid)*8 + n];
    const size_t rbase = (size_t)ib*LSEQ*DIMC;
    const size_t zbase = (size_t)bb*LSEQ*512 + m*256 + 128;
    #pragma unroll 2
    for (int s = 0; s < LC; s++){
        int j = c*LC + s;
        int l = d ? (LSEQ-1-j) : j;
        size_t ro = rbase + (size_t)l*DIMC + tid;
        float dtv = bf2f(dty[ro]);
        float uv  = bf2f(xc[ro]);
        const float* bp = bcb + ((size_t)ib*LSEQ + l)*16;
        float4 bA = *(const float4*)bp;
        float4 bB = *(const float4*)(bp+4);
        float4 cA = *(const float4*)(bp+8);
        float4 cB = *(const float4*)(bp+12);
        float bv[8] = {bA.x,bA.y,bA.z,bA.w,bB.x,bB.y,bB.z,bB.w};
        float cv[8] = {cA.x,cA.y,cA.z,cA.w,cB.x,cB.y,cB.z,cB.w};
        float du = dtv*uv;
        float y = uv*Dv;
        #pragma unroll
        for (int n = 0; n < 8; n++){
            float a = __expf(dtv*Av[n]);
            h[n] = a*h[n] + du*bv[n];
            y += h[n]*cv[n];
        }
        float zv = bf2f(xz[zbase + (size_t)l*512 + tid]);
        y *= zv * sigf(zv);
        dty[ro] = f2bf(y);
    }
}

// ---------------------------------------------------------------- out_proj MFMA + diff + LN + add x + LN + T-store
__global__ __launch_bounds__(256,2) void k_final(const unsigned short* __restrict__ y,
    const unsigned short* __restrict__ owb, const float* __restrict__ x, const float* __restrict__ lamp,
    const float* __restrict__ sw, const float* __restrict__ sb,
    const float* __restrict__ n2w, const float* __restrict__ n2b, float* __restrict__ outp)
{
    __shared__ __align__(16) char smem[52480];
    unsigned short* Ast = (unsigned short*)smem;             // phase 1: [2*64][KP] = 33792 B
    float* yt            = (float*)smem;                     // phase 2: [64][129] f32 = 33024 B
    unsigned short* xtb  = (unsigned short*)(smem + 33024);  // [64][132] bf16 = 16896 B
    float* red1          = (float*)(smem + 49920);           // 1024 B
    float* red2          = (float*)(smem + 50944);           // 1024 B
    float* stt           = (float*)(smem + 51968);           //  512 B  (total 52480)
    const int bb = blockIdx.y;
    const int l0 = blockIdx.x * 64;                  // grid.x = 192
    const int tid = threadIdx.x;
    const float lam = *lamp;
    #pragma unroll
    for (int p = 0; p < 8; p++){
        int idx = p*256 + tid; int mm = idx >> 10; int li = (idx >> 4) & 63; int g = (idx & 15)*8;
        // NOTE: scan3 stores backward-direction y at ORIGINAL l coordinates already
        // (it walks l descending but writes at l). Both directions are read at l0+li.
        // Round-3 regression was an erroneous (LSEQ-1-l0-li) mirror here.
        uint4 vf = *(const uint4*)&y[(((size_t)(mm*2+0)*NB + bb)*LSEQ + l0 + li)*DIMC + g];
        uint4 vb = *(const uint4*)&y[(((size_t)(mm*2+1)*NB + bb)*LSEQ + l0 + li)*DIMC + g];
        const unsigned short* uf = (const unsigned short*)&vf;
        const unsigned short* ub = (const unsigned short*)&vb;
        unsigned short o[8];
        #pragma unroll
        for (int j = 0; j < 8; j++) o[j] = f2bf(bf2f(uf[j]) + bf2f(ub[j]));
        *(uint2*)&Ast[(mm*64 + li)*KP + g]     = *(uint2*)&o[0];
        *(uint2*)&Ast[(mm*64 + li)*KP + g + 4] = *(uint2*)&o[4];
    }
    __syncthreads();
    const int lane = tid & 63, w = tid >> 6;
    const int m15 = lane & 15, q = lane >> 4;
    f4_t zf = {0.f,0.f,0.f,0.f};
    f4_t acc[2][8];
    #pragma unroll
    for (int i = 0; i < 2; i++)
        #pragma unroll
        for (int j = 0; j < 8; j++) acc[i][j] = zf;
    #pragma unroll
    for (int ks = 0; ks < 4; ks++){
        int k0 = ks*32 + q*8;
        bf16x8 a0 = ld_frag8(&Ast[(       w*16 + m15)*KP + k0]);
        bf16x8 a1 = ld_frag8(&Ast[(64   + w*16 + m15)*KP + k0]);
        #pragma unroll
        for (int nt = 0; nt < 8; nt++){
            bf16x8 b0 = ld_frag16g(&owb[((size_t)0*DIMC + nt*16 + m15)*DIMC + k0]);
            bf16x8 b1 = ld_frag16g(&owb[((size_t)1*DIMC + nt*16 + m15)*DIMC + k0]);
            acc[0][nt] = __builtin_amdgcn_mfma_f32_16x16x32_bf16(a0, b0, acc[0][nt], 0,0,0);
            acc[1][nt] = __builtin_amdgcn_mfma_f32_16x16x32_bf16(a1, b1, acc[1][nt], 0,0,0);
        }
    }
    __syncthreads();                                 // Ast dead; epilogue overlays
    #pragma unroll
    for (int nt = 0; nt < 8; nt++){
        int row = w*16 + q*4;
        int col = nt*16 + m15;
        #pragma unroll
        for (int i = 0; i < 4; i++)
            yt[(row+i)*129 + col] = acc[0][nt][i] - lam*acc[1][nt][i];
    }
    {
        const int li = tid & 63, cg = tid >> 6;
        #pragma unroll
        for (int p = 0; p < 32; p++){
            int c = p*4 + cg;
            xtb[li*132 + c] = f2bf(x[(size_t)bb*DIMC*LSEQ + (size_t)c*LSEQ + l0 + li]);
        }
    }
    __syncthreads();
    const int r = tid & 63, g = tid >> 6;            // 4 groups of 32 cols
    float s = 0.f, s2 = 0.f;
    #pragma unroll
    for (int k = 0; k < 32; k++){ float v = yt[r*129 + g*32 + k]; s += v; s2 += v*v; }
    red1[g*64 + r] = s; red2[g*64 + r] = s2;
    __syncthreads();
    if (tid < 64){
        float ss = 0.f, ss2 = 0.f;
        #pragma unroll
        for (int gg = 0; gg < 4; gg++){ ss += red1[gg*64 + tid]; ss2 += red2[gg*64 + tid]; }
        float mu = ss*(1.f/128.f);
        float var = ss2*(1.f/128.f) - mu*mu;
        stt[tid*2] = mu; stt[tid*2+1] = rsqrtf(var + EPSV);
    }
    __syncthreads();
    float mu1 = stt[r*2], rs1 = stt[r*2+1];
    s = 0.f; s2 = 0.f;
    #pragma unroll
    for (int k = 0; k < 32; k++){
        int c = g*32 + k;
        float v = (yt[r*129+c] - mu1)*rs1*sw[c] + sb[c] + bf2f(xtb[r*132+c]);
        yt[r*129+c] = v;
        s += v; s2 += v*v;
    }
    __syncthreads();
    red1[g*64 + r] = s; red2[g*64 + r] = s2;
    __syncthreads();
    if (tid < 64){
        float ss = 0.f, ss2 = 0.f;
        #pragma unroll
        for (int gg = 0; gg < 4; gg++){ ss += red1[gg*64 + tid]; ss2 += red2[gg*64 + tid]; }
        float mu = ss*(1.f/128.f);
        float var = ss2*(1.f/128.f) - mu*mu;
        stt[tid*2] = mu; stt[tid*2+1] = rsqrtf(var + EPSV);
    }
    __syncthreads();
    float mu2 = stt[r*2], rs2 = stt[r*2+1];
    #pragma unroll
    for (int k = 0; k < 32; k++){
        int c = g*32 + k;
        float o = (yt[r*129+c] - mu2)*rs2*n2w[c] + n2b[c];
        outp[(size_t)bb*DIMC*LSEQ + (size_t)c*LSEQ + l0 + r] = o;
    }
}

// ----------------------------------------------------------------
extern "C" void kernel_launch(void* const* d_in, const int* in_sizes, int n_in,
                              void* d_out, int out_size, void* d_ws, size_t ws_size,
                              hipStream_t stream)
{
    const float* x    = (const float*)d_in[0];
    const float* n1w  = (const float*)d_in[1];
    const float* n1b  = (const float*)d_in[2];
    const float* n2w  = (const float*)d_in[3];
    const float* n2b  = (const float*)d_in[4];
    const float* slw  = (const float*)d_in[5];
    const float* slb  = (const float*)d_in[6];
    const float* lq   = (const float*)d_in[7];
    const float* wi   = (const float*)d_in[8];
    const float* cw   = (const float*)d_in[9];
    const float* cb   = (const float*)d_in[10];
    const float* xpw  = (const float*)d_in[11];
    const float* dtw  = (const float*)d_in[12];
    const float* dtb  = (const float*)d_in[13];
    const float* alog = (const float*)d_in[14];
    const float* dvec = (const float*)d_in[15];
    const float* ow   = (const float*)d_in[16];

    float* ws = (float*)d_ws;
    unsigned short* xn    = (unsigned short*)(ws);             // 1,572,864 f (dead after inproj)
    float*          st1   = ws;                                // overlay on xn (scan phase)
    unsigned short* xz    = (unsigned short*)(ws + 1572864);   // 6,291,456 f
    unsigned short* xc    = (unsigned short*)(ws + 7864320);   // 6,291,456 f
    unsigned short* dty   = (unsigned short*)(ws + 14155776);  // 6,291,456 f
    float*          bcb   = ws + 20447232;                     // 1,572,864 f
    float*          hst   = ws + 22020096;                     //   786,432 f
    unsigned short* wallb = (unsigned short*)(ws + 22806528);  //    36,864 f
    unsigned short* wib   = (unsigned short*)(ws + 22843392);  //    32,768 f
    unsigned short* owb   = (unsigned short*)(ws + 22876160);  //    16,384 f
    float*          lam   = ws + 22892544;                     //         1

    k_lam   <<<1, 64, 0, stream>>>(lq, lam);
    k_wall  <<<dim3(4,144), 128, 0, stream>>>(dtw, xpw, wallb);
    k_prep  <<<96, 256, 0, stream>>>(wi, ow, wib, owb);
    k_normT <<<384, 256, 0, stream>>>(x, n1w, n1b, xn);
    k_inproj<<<dim3(192, 4), 256, 0, stream>>>(xn, wib, xz);
    k_conv  <<<2*NB*(LSEQ/64), 256, 0, stream>>>(xz, cw, cb, xc);
    k_xproj <<<dim3(96, 8), 256, 0, stream>>>(xc, wallb, dtb, dty, bcb);
    k_scan1 <<<8*NCH, 128, 0, stream>>>(dty, xc, bcb, alog, st1);
    k_scan2 <<<32, 256, 0, stream>>>(st1, hst);
    k_scan3 <<<8*NCH, 128, 0, stream>>>(dty, xc, bcb, xz, hst, alog, dvec);
    k_final <<<dim3(192, 2), 256, 0, stream>>>(dty, owb, x, lam, slw, slb, n2w, n2b, (float*)d_out);
}

// Round 7
// 298.318 us; speedup vs baseline: 3.8995x; 1.0628x over previous
//
#include <hip/hip_runtime.h>
#include <math.h>

#define DIMC 128
#define LSEQ 12288
#define NB 2
#define BLR 24576   // NB*LSEQ
#define EPSV 1e-5f
#define NCH 256     // scan chunks per row (16 waves/CU at 128-thr blocks)
#define LC 48       // chunk length (NCH*LC = LSEQ)
#define KP 132      // LDS row pad (ushorts) for MFMA staging

typedef __bf16 bf16x8 __attribute__((ext_vector_type(8)));
typedef __attribute__((ext_vector_type(4))) float f4_t;

__device__ __forceinline__ float sigf(float x){ return 1.f/(1.f+__expf(-x)); }
__device__ __forceinline__ float softplusf(float x){ return fmaxf(x,0.f) + log1pf(__expf(-fabsf(x))); }
__device__ __forceinline__ float bf2f(unsigned short u){
    union { unsigned int i; float f; } v; v.i = ((unsigned int)u) << 16; return v.f;
}
__device__ __forceinline__ unsigned short f2bf(float f){
    union { float f; unsigned int i; } v; v.f = f;
    unsigned int b = v.i + 0x7FFFu + ((v.i >> 16) & 1u);
    return (unsigned short)(b >> 16);
}
__device__ __forceinline__ bf16x8 ld_frag8(const unsigned short* p){   // 8B-aligned LDS
    union { uint2 u[2]; bf16x8 v; } r;
    r.u[0] = *(const uint2*)(p);
    r.u[1] = *(const uint2*)(p+4);
    return r.v;
}
__device__ __forceinline__ bf16x8 ld_frag16g(const unsigned short* p){ // 16B-aligned global
    union { uint4 u; bf16x8 v; } r; r.u = *(const uint4*)p; return r.v;
}

// ---------------------------------------------------------------- lam = sigmoid(sum(lambda_q))
__global__ void k_lam(const float* __restrict__ lq, float* __restrict__ lam){
    int lane = threadIdx.x;
    float v = lq[lane] + lq[lane+64];
    for (int m = 32; m; m >>= 1) v += __shfl_xor(v, m);
    if (lane == 0) *lam = 1.f/(1.f+__expf(-v));
}

// ---------------------------------------------------------------- W_all[inst][144][128] (bf16)
__global__ void k_wall(const float* __restrict__ dtw, const float* __restrict__ xpw,
                       unsigned short* __restrict__ wallb){
    int inst = blockIdx.x, j = blockIdx.y, k = threadIdx.x;  // grid (4,144), block 128
    const float* xp = xpw + (size_t)inst*24*128;
    float v;
    if (j < 128){
        const float* dw = dtw + (size_t)inst*128*8 + (size_t)j*8;
        v = 0.f;
        #pragma unroll
        for (int r = 0; r < 8; r++) v += dw[r]*xp[r*128 + k];
    } else {
        v = xp[(8 + (j-128))*128 + k];
    }
    wallb[((size_t)inst*144 + j)*128 + k] = f2bf(v);
}

// ---------------------------------------------------------------- wi, ow -> bf16
__global__ __launch_bounds__(256) void k_prep(const float* __restrict__ wi, const float* __restrict__ ow,
    unsigned short* __restrict__ wib, unsigned short* __restrict__ owb){
    int idx = (blockIdx.x*256 + threadIdx.x)*4;   // grid 96 -> 98304 elems
    const float* src; unsigned short* dst; int off;
    if (idx < 65536){ src = wi;  dst = wib; off = idx; }
    else            { src = ow;  dst = owb; off = idx - 65536; }
    float4 v = *(const float4*)&src[off];
    ushort4 o; o.x=f2bf(v.x); o.y=f2bf(v.y); o.z=f2bf(v.z); o.w=f2bf(v.w);
    *(ushort4*)&dst[off] = o;
}

// ---------------------------------------------------------------- LN1 (stats fused) + transpose -> xn bf16 [b*l][128]
__global__ __launch_bounds__(256) void k_normT(const float* __restrict__ x,
    const float* __restrict__ w1, const float* __restrict__ b1, unsigned short* __restrict__ xn)
{
    __shared__ float t[64*129];
    __shared__ float red1[256], red2[256];
    __shared__ float stt[128];
    const int bb = blockIdx.x / 192;
    const int l0 = (blockIdx.x % 192) * 64;
    const int tid = threadIdx.x;
    const int li = tid & 63, cg = tid >> 6;
    #pragma unroll
    for (int p = 0; p < 32; p++){
        int c = p*4 + cg;
        t[li*129 + c] = x[(size_t)bb*DIMC*LSEQ + (size_t)c*LSEQ + l0 + li];
    }
    __syncthreads();
    {
        int r = tid >> 2, qg = tid & 3;
        float s = 0.f, s2 = 0.f;
        #pragma unroll
        for (int j = 0; j < 32; j++){ float v = t[r*129 + qg*32 + j]; s += v; s2 += v*v; }
        red1[qg*64 + r] = s; red2[qg*64 + r] = s2;
    }
    __syncthreads();
    if (tid < 64){
        float s = 0.f, s2 = 0.f;
        #pragma unroll
        for (int g = 0; g < 4; g++){ s += red1[g*64 + tid]; s2 += red2[g*64 + tid]; }
        float mu = s*(1.f/128.f);
        float var = s2*(1.f/128.f) - mu*mu;
        stt[tid*2] = mu; stt[tid*2+1] = rsqrtf(var + EPSV);
    }
    __syncthreads();
    const int c2 = (tid & 63)*2, lg = tid >> 6;
    #pragma unroll
    for (int p = 0; p < 16; p++){
        int l = p*4 + lg;
        float mu = stt[l*2], rs = stt[l*2+1];
        float v0 = (t[l*129 + c2    ] - mu)*rs*w1[c2    ] + b1[c2    ];
        float v1 = (t[l*129 + c2 + 1] - mu)*rs*w1[c2 + 1] + b1[c2 + 1];
        unsigned int o = (unsigned int)f2bf(v0) | ((unsigned int)f2bf(v1) << 16);
        *(unsigned int*)&xn[(size_t)(bb*LSEQ + l0 + l)*DIMC + c2] = o;
    }
}

// ---------------------------------------------------------------- in_proj MFMA: [128m x 128n x 128k] tiles
__global__ __launch_bounds__(256,2) void k_inproj(const unsigned short* __restrict__ xn,
    const unsigned short* __restrict__ wib, unsigned short* __restrict__ xz)
{
    __shared__ __align__(16) unsigned short As[128*KP];   // 33792 B
    const int row0 = blockIdx.x * 128;   // grid.x = 192
    const int j0   = blockIdx.y * 128;   // grid.y = 4
    const int tid = threadIdx.x;
    #pragma unroll
    for (int p = 0; p < 8; p++){
        int idx = p*256 + tid; int li = idx >> 4; int g = (idx & 15)*8;
        uint4 va = *(const uint4*)&xn[(size_t)(row0+li)*DIMC + g];
        *(uint2*)&As[li*KP + g]     = make_uint2(va.x, va.y);
        *(uint2*)&As[li*KP + g + 4] = make_uint2(va.z, va.w);
    }
    __syncthreads();
    const int lane = tid & 63, w = tid >> 6;
    const int m15 = lane & 15, q = lane >> 4;
    f4_t zf = {0.f,0.f,0.f,0.f};
    f4_t acc[2][8];
    #pragma unroll
    for (int i = 0; i < 2; i++)
        #pragma unroll
        for (int j = 0; j < 8; j++) acc[i][j] = zf;
    #pragma unroll
    for (int ks = 0; ks < 4; ks++){
        int k0 = ks*32 + q*8;
        bf16x8 a0 = ld_frag8(&As[(w*32      + m15)*KP + k0]);
        bf16x8 a1 = ld_frag8(&As[(w*32 + 16 + m15)*KP + k0]);
        #pragma unroll
        for (int nt = 0; nt < 8; nt++){
            bf16x8 b = ld_frag16g(&wib[(size_t)(j0 + nt*16 + m15)*DIMC + k0]);
            acc[0][nt] = __builtin_amdgcn_mfma_f32_16x16x32_bf16(a0, b, acc[0][nt], 0,0,0);
            acc[1][nt] = __builtin_amdgcn_mfma_f32_16x16x32_bf16(a1, b, acc[1][nt], 0,0,0);
        }
    }
    __syncthreads();
    unsigned short* ep = As;             // reuse
    #pragma unroll
    for (int mi = 0; mi < 2; mi++)
        #pragma unroll
        for (int nt = 0; nt < 8; nt++){
            int row = w*32 + mi*16 + q*4;
            int col = nt*16 + m15;
            #pragma unroll
            for (int i = 0; i < 4; i++)
                ep[(row+i)*KP + col] = f2bf(acc[mi][nt][i]);
        }
    __syncthreads();
    #pragma unroll
    for (int p = 0; p < 8; p++){
        int idx = p*256 + tid; int li = idx >> 4; int g = (idx & 15)*8;
        uint2 u0 = *(const uint2*)&ep[li*KP + g];
        uint2 u1 = *(const uint2*)&ep[li*KP + g + 4];
        uint4 o; o.x=u0.x; o.y=u0.y; o.z=u1.x; o.w=u1.y;
        *(uint4*)&xz[(size_t)(row0+li)*512 + j0 + g] = o;
    }
}

// ---------------------------------------------------------------- conv (both directions) + silu
__global__ __launch_bounds__(256) void k_conv(const unsigned short* __restrict__ xz,
    const float* __restrict__ cw, const float* __restrict__ cb, unsigned short* __restrict__ xc)
{
    __shared__ unsigned short tile[70][144];
    const int bid = blockIdx.x;                // grid = 2*2*192
    const int lt = bid % 192;
    const int bb = (bid/192) % NB;
    const int m  = bid / (192*NB);
    const int l0 = lt * 64;
    const int tid = threadIdx.x;
    for (int idx = tid; idx < 70*16; idx += 256){
        int r = idx >> 4, cq = idx & 15;
        int l = l0 - 3 + r;
        uint4 v = make_uint4(0,0,0,0);
        if (l >= 0 && l < LSEQ)
            v = *(const uint4*)&xz[((size_t)(bb*LSEQ + l))*512 + m*256 + cq*8];
        *(uint4*)&tile[r][cq*8] = v;
    }
    __syncthreads();
    const int dimi = tid & 127, lg = tid >> 7;
    float w0a[4], w1a[4];
    #pragma unroll
    for (int k = 0; k < 4; k++){
        w0a[k] = cw[((size_t)(m*2+0)*DIMC + dimi)*4 + k];
        w1a[k] = cw[((size_t)(m*2+1)*DIMC + dimi)*4 + k];
    }
    const float b0 = cb[(m*2+0)*DIMC + dimi];
    const float b1v = cb[(m*2+1)*DIMC + dimi];
    for (int p = 0; p < 32; p++){
        int li = p*2 + lg;
        float t0 = bf2f(tile[li  ][dimi]);
        float t1 = bf2f(tile[li+1][dimi]);
        float t2 = bf2f(tile[li+2][dimi]);
        float t3 = bf2f(tile[li+3][dimi]);
        float t4 = bf2f(tile[li+4][dimi]);
        float t5 = bf2f(tile[li+5][dimi]);
        float t6 = bf2f(tile[li+6][dimi]);
        float v0 = b0  + w0a[0]*t0 + w0a[1]*t1 + w0a[2]*t2 + w0a[3]*t3;
        float v1 = b1v + w1a[3]*t3 + w1a[2]*t4 + w1a[1]*t5 + w1a[0]*t6;
        v0 = v0 * sigf(v0);
        v1 = v1 * sigf(v1);
        xc[(((size_t)(m*2+0)*NB + bb)*LSEQ + l0 + li)*DIMC + dimi] = f2bf(v0);
        xc[(((size_t)(m*2+1)*NB + bb)*LSEQ + l0 + li)*DIMC + dimi] = f2bf(v1);
    }
}

// ---------------------------------------------------------------- x_proj MFMA: [128m x 144n x 128k] per ib
__global__ __launch_bounds__(256,2) void k_xproj(const unsigned short* __restrict__ xc,
    const unsigned short* __restrict__ wallb, const float* __restrict__ dtb,
    unsigned short* __restrict__ dty, float* __restrict__ bcb)
{
    __shared__ __align__(16) unsigned short As[128*KP];   // 33792 B
    __shared__ __align__(16) float bq[128*17];            //  8704 B
    const int row0 = blockIdx.x * 128;   // grid.x = 96
    const int ib   = blockIdx.y;         // 0..7
    const int inst = ib >> 1;
    const int tid = threadIdx.x;
    const size_t abase = (size_t)ib * LSEQ * DIMC;
    #pragma unroll
    for (int p = 0; p < 8; p++){
        int idx = p*256 + tid; int li = idx >> 4; int g = (idx & 15)*8;
        uint4 va = *(const uint4*)&xc[abase + (size_t)(row0+li)*DIMC + g];
        *(uint2*)&As[li*KP + g]     = make_uint2(va.x, va.y);
        *(uint2*)&As[li*KP + g + 4] = make_uint2(va.z, va.w);
    }
    __syncthreads();
    const int lane = tid & 63, w = tid >> 6;
    const int m15 = lane & 15, q = lane >> 4;
    f4_t zf = {0.f,0.f,0.f,0.f};
    f4_t acc[2][9];
    #pragma unroll
    for (int i = 0; i < 2; i++)
        #pragma unroll
        for (int j = 0; j < 9; j++) acc[i][j] = zf;
    #pragma unroll
    for (int ks = 0; ks < 4; ks++){
        int k0 = ks*32 + q*8;
        bf16x8 a0 = ld_frag8(&As[(w*32      + m15)*KP + k0]);
        bf16x8 a1 = ld_frag8(&As[(w*32 + 16 + m15)*KP + k0]);
        #pragma unroll
        for (int nt = 0; nt < 9; nt++){
            bf16x8 b = ld_frag16g(&wallb[((size_t)inst*144 + nt*16 + m15)*DIMC + k0]);
            acc[0][nt] = __builtin_amdgcn_mfma_f32_16x16x32_bf16(a0, b, acc[0][nt], 0,0,0);
            acc[1][nt] = __builtin_amdgcn_mfma_f32_16x16x32_bf16(a1, b, acc[1][nt], 0,0,0);
        }
    }
    __syncthreads();
    unsigned short* ep = As;             // dt bf16 [128][KP]
    #pragma unroll
    for (int mi = 0; mi < 2; mi++){
        int row = w*32 + mi*16 + q*4;
        #pragma unroll
        for (int nt = 0; nt < 8; nt++){
            int col = nt*16 + m15;
            float bias = dtb[inst*DIMC + col];
            #pragma unroll
            for (int i = 0; i < 4; i++)
                ep[(row+i)*KP + col] = f2bf(softplusf(acc[mi][nt][i] + bias));
        }
        #pragma unroll
        for (int i = 0; i < 4; i++)
            bq[(row+i)*17 + m15] = acc[mi][8][i];
    }
    __syncthreads();
    #pragma unroll
    for (int p = 0; p < 8; p++){
        int idx = p*256 + tid; int li = idx >> 4; int g = (idx & 15)*8;
        uint2 u0 = *(const uint2*)&ep[li*KP + g];
        uint2 u1 = *(const uint2*)&ep[li*KP + g + 4];
        uint4 o; o.x=u0.x; o.y=u0.y; o.z=u1.x; o.w=u1.y;
        *(uint4*)&dty[abase + (size_t)(row0+li)*DIMC + g] = o;
    }
    #pragma unroll
    for (int p = 0; p < 2; p++){
        int idx = p*256 + tid; int li = idx >> 2; int c4 = (idx & 3)*4;
        float4 v;
        v.x = bq[li*17 + c4]; v.y = bq[li*17 + c4 + 1];
        v.z = bq[li*17 + c4 + 2]; v.w = bq[li*17 + c4 + 3];
        *(float4*)&bcb[((size_t)ib*LSEQ + row0 + li)*16 + c4] = v;
    }
}

// ---------------------------------------------------------------- scan S1 (per-chunk reduce)
__global__ __launch_bounds__(128) void k_scan1(const unsigned short* __restrict__ dt,
    const unsigned short* __restrict__ xc, const float* __restrict__ bcb,
    const float* __restrict__ alog, float* __restrict__ st)
{
    const int ib = blockIdx.x & 7;
    const int c  = blockIdx.x >> 3;            // 0..NCH-1
    const int inst = ib >> 1;
    const int d = inst & 1;
    const int tid = threadIdx.x;
    float Av[8];
    #pragma unroll
    for (int n = 0; n < 8; n++) Av[n] = -__expf(alog[((size_t)inst*DIMC + tid)*8 + n]);
    const size_t rbase = (size_t)ib*LSEQ*DIMC;
    float Ac[8], Bc[8];
    #pragma unroll
    for (int n = 0; n < 8; n++){ Ac[n] = 1.f; Bc[n] = 0.f; }
    #pragma unroll 4
    for (int s = 0; s < LC; s++){
        int j = c*LC + s;
        int l = d ? (LSEQ-1-j) : j;
        size_t ro = rbase + (size_t)l*DIMC + tid;
        float dtv = bf2f(dt[ro]);
        float uv  = bf2f(xc[ro]);
        const float* bp = bcb + ((size_t)ib*LSEQ + l)*16;
        float4 bA = *(const float4*)bp;
        float4 bB = *(const float4*)(bp+4);
        float bv[8] = {bA.x,bA.y,bA.z,bA.w,bB.x,bB.y,bB.z,bB.w};
        float du = dtv*uv;
        #pragma unroll
        for (int n = 0; n < 8; n++){
            float a = __expf(dtv*Av[n]);
            Bc[n] = a*Bc[n] + du*bv[n];
            Ac[n] *= a;
        }
    }
    float* so = st + (((size_t)ib*NCH + c)*DIMC + tid)*16;
    #pragma unroll
    for (int n = 0; n < 8; n++){ so[n] = Ac[n]; so[8+n] = Bc[n]; }
}

// ---------------------------------------------------------------- scan S2 (cross-chunk exclusive prefix)
__global__ __launch_bounds__(256) void k_scan2(const float* __restrict__ st, float* __restrict__ hst){
    int gid = blockIdx.x*256 + threadIdx.x;    // 8192 threads
    int ib = gid >> 10;
    int r  = gid & 1023;
    int dim = r >> 3, n = r & 7;
    float Bp = 0.f;
    for (int c = 0; c < NCH; c++){
        size_t o = (((size_t)ib*NCH + c)*DIMC + dim)*16;
        float A = st[o+n], Bv = st[o+8+n];
        hst[(((size_t)ib*NCH + c)*DIMC + dim)*8 + n] = Bp;
        Bp = A*Bp + Bv;
    }
}

// ---------------------------------------------------------------- scan S3 (replay, y in place over dt)
__global__ __launch_bounds__(128) void k_scan3(unsigned short* __restrict__ dty,
    const unsigned short* __restrict__ xc, const float* __restrict__ bcb,
    const unsigned short* __restrict__ xz, const float* __restrict__ hst,
    const float* __restrict__ alog, const float* __restrict__ dvec)
{
    const int ib = blockIdx.x & 7;
    const int c  = blockIdx.x >> 3;
    const int inst = ib >> 1, bb = ib & 1;
    const int m = inst >> 1, d = inst & 1;
    const int tid = threadIdx.x;
    float Av[8];
    #pragma unroll
    for (int n = 0; n < 8; n++) Av[n] = -__expf(alog[((size_t)inst*DIMC + tid)*8 + n]);
    const float Dv = dvec[inst*DIMC + tid];
    float h[8];
    #pragma unroll
    for (int n = 0; n < 8; n++) h[n] = hst[(((size_t)ib*NCH + c)*DIMC + tid)*8 + n];
    const size_t rbase = (size_t)ib*LSEQ*DIMC;
    const size_t zbase = (size_t)bb*LSEQ*512 + m*256 + 128;
    #pragma unroll 2
    for (int s = 0; s < LC; s++){
        int j = c*LC + s;
        int l = d ? (LSEQ-1-j) : j;
        size_t ro = rbase + (size_t)l*DIMC + tid;
        float dtv = bf2f(dty[ro]);
        float uv  = bf2f(xc[ro]);
        const float* bp = bcb + ((size_t)ib*LSEQ + l)*16;
        float4 bA = *(const float4*)bp;
        float4 bB = *(const float4*)(bp+4);
        float4 cA = *(const float4*)(bp+8);
        float4 cB = *(const float4*)(bp+12);
        float bv[8] = {bA.x,bA.y,bA.z,bA.w,bB.x,bB.y,bB.z,bB.w};
        float cv[8] = {cA.x,cA.y,cA.z,cA.w,cB.x,cB.y,cB.z,cB.w};
        float du = dtv*uv;
        float y = uv*Dv;
        #pragma unroll
        for (int n = 0; n < 8; n++){
            float a = __expf(dtv*Av[n]);
            h[n] = a*h[n] + du*bv[n];
            y += h[n]*cv[n];
        }
        float zv = bf2f(xz[zbase + (size_t)l*512 + tid]);
        y *= zv * sigf(zv);
        dty[ro] = f2bf(y);
    }
}

// ---------------------------------------------------------------- out_proj MFMA + diff + LN + add x + LN + T-store
__global__ __launch_bounds__(256,2) void k_final(const unsigned short* __restrict__ y,
    const unsigned short* __restrict__ owb, const float* __restrict__ x, const float* __restrict__ lamp,
    const float* __restrict__ sw, const float* __restrict__ sb,
    const float* __restrict__ n2w, const float* __restrict__ n2b, float* __restrict__ outp)
{
    __shared__ __align__(16) char smem[52480];
    unsigned short* Ast = (unsigned short*)smem;             // phase 1: [2*64][KP] = 33792 B
    float* yt            = (float*)smem;                     // phase 2: [64][129] f32 = 33024 B
    unsigned short* xtb  = (unsigned short*)(smem + 33024);  // [64][132] bf16 = 16896 B
    float* red1          = (float*)(smem + 49920);           // 1024 B
    float* red2          = (float*)(smem + 50944);           // 1024 B
    float* stt           = (float*)(smem + 51968);           //  512 B
    const int bb = blockIdx.y;
    const int l0 = blockIdx.x * 64;                  // grid.x = 192
    const int tid = threadIdx.x;
    const float lam = *lamp;
    #pragma unroll
    for (int p = 0; p < 8; p++){
        int idx = p*256 + tid; int mm = idx >> 10; int li = (idx >> 4) & 63; int g = (idx & 15)*8;
        // scan3 stores backward-direction y at ORIGINAL l coords; both read at l0+li.
        uint4 vf = *(const uint4*)&y[(((size_t)(mm*2+0)*NB + bb)*LSEQ + l0 + li)*DIMC + g];
        uint4 vb = *(const uint4*)&y[(((size_t)(mm*2+1)*NB + bb)*LSEQ + l0 + li)*DIMC + g];
        const unsigned short* uf = (const unsigned short*)&vf;
        const unsigned short* ub = (const unsigned short*)&vb;
        unsigned short o[8];
        #pragma unroll
        for (int j = 0; j < 8; j++) o[j] = f2bf(bf2f(uf[j]) + bf2f(ub[j]));
        *(uint2*)&Ast[(mm*64 + li)*KP + g]     = *(uint2*)&o[0];
        *(uint2*)&Ast[(mm*64 + li)*KP + g + 4] = *(uint2*)&o[4];
    }
    __syncthreads();
    const int lane = tid & 63, w = tid >> 6;
    const int m15 = lane & 15, q = lane >> 4;
    f4_t zf = {0.f,0.f,0.f,0.f};
    f4_t acc[2][8];
    #pragma unroll
    for (int i = 0; i < 2; i++)
        #pragma unroll
        for (int j = 0; j < 8; j++) acc[i][j] = zf;
    #pragma unroll
    for (int ks = 0; ks < 4; ks++){
        int k0 = ks*32 + q*8;
        bf16x8 a0 = ld_frag8(&Ast[(       w*16 + m15)*KP + k0]);
        bf16x8 a1 = ld_frag8(&Ast[(64   + w*16 + m15)*KP + k0]);
        #pragma unroll
        for (int nt = 0; nt < 8; nt++){
            bf16x8 b0 = ld_frag16g(&owb[((size_t)0*DIMC + nt*16 + m15)*DIMC + k0]);
            bf16x8 b1 = ld_frag16g(&owb[((size_t)1*DIMC + nt*16 + m15)*DIMC + k0]);
            acc[0][nt] = __builtin_amdgcn_mfma_f32_16x16x32_bf16(a0, b0, acc[0][nt], 0,0,0);
            acc[1][nt] = __builtin_amdgcn_mfma_f32_16x16x32_bf16(a1, b1, acc[1][nt], 0,0,0);
        }
    }
    __syncthreads();                                 // Ast dead; epilogue overlays
    #pragma unroll
    for (int nt = 0; nt < 8; nt++){
        int row = w*16 + q*4;
        int col = nt*16 + m15;
        #pragma unroll
        for (int i = 0; i < 4; i++)
            yt[(row+i)*129 + col] = acc[0][nt][i] - lam*acc[1][nt][i];
    }
    {
        const int li = tid & 63, cg = tid >> 6;
        #pragma unroll
        for (int p = 0; p < 32; p++){
            int c = p*4 + cg;
            xtb[li*132 + c] = f2bf(x[(size_t)bb*DIMC*LSEQ + (size_t)c*LSEQ + l0 + li]);
        }
    }
    __syncthreads();
    const int r = tid & 63, g = tid >> 6;            // 4 groups of 32 cols
    float s = 0.f, s2 = 0.f;
    #pragma unroll
    for (int k = 0; k < 32; k++){ float v = yt[r*129 + g*32 + k]; s += v; s2 += v*v; }
    red1[g*64 + r] = s; red2[g*64 + r] = s2;
    __syncthreads();
    if (tid < 64){
        float ss = 0.f, ss2 = 0.f;
        #pragma unroll
        for (int gg = 0; gg < 4; gg++){ ss += red1[gg*64 + tid]; ss2 += red2[gg*64 + tid]; }
        float mu = ss*(1.f/128.f);
        float var = ss2*(1.f/128.f) - mu*mu;
        stt[tid*2] = mu; stt[tid*2+1] = rsqrtf(var + EPSV);
    }
    __syncthreads();
    float mu1 = stt[r*2], rs1 = stt[r*2+1];
    s = 0.f; s2 = 0.f;
    #pragma unroll
    for (int k = 0; k < 32; k++){
        int c = g*32 + k;
        float v = (yt[r*129+c] - mu1)*rs1*sw[c] + sb[c] + bf2f(xtb[r*132+c]);
        yt[r*129+c] = v;
        s += v; s2 += v*v;
    }
    __syncthreads();
    red1[g*64 + r] = s; red2[g*64 + r] = s2;
    __syncthreads();
    if (tid < 64){
        float ss = 0.f, ss2 = 0.f;
        #pragma unroll
        for (int gg = 0; gg < 4; gg++){ ss += red1[gg*64 + tid]; ss2 += red2[gg*64 + tid]; }
        float mu = ss*(1.f/128.f);
        float var = ss2*(1.f/128.f) - mu*mu;
        stt[tid*2] = mu; stt[tid*2+1] = rsqrtf(var + EPSV);
    }
    __syncthreads();
    float mu2 = stt[r*2], rs2 = stt[r*2+1];
    #pragma unroll
    for (int k = 0; k < 32; k++){
        int c = g*32 + k;
        float o = (yt[r*129+c] - mu2)*rs2*n2w[c] + n2b[c];
        outp[(size_t)bb*DIMC*LSEQ + (size_t)c*LSEQ + l0 + r] = o;
    }
}

// ----------------------------------------------------------------
extern "C" void kernel_launch(void* const* d_in, const int* in_sizes, int n_in,
                              void* d_out, int out_size, void* d_ws, size_t ws_size,
                              hipStream_t stream)
{
    const float* x    = (const float*)d_in[0];
    const float* n1w  = (const float*)d_in[1];
    const float* n1b  = (const float*)d_in[2];
    const float* n2w  = (const float*)d_in[3];
    const float* n2b  = (const float*)d_in[4];
    const float* slw  = (const float*)d_in[5];
    const float* slb  = (const float*)d_in[6];
    const float* lq   = (const float*)d_in[7];
    const float* wi   = (const float*)d_in[8];
    const float* cw   = (const float*)d_in[9];
    const float* cb   = (const float*)d_in[10];
    const float* xpw  = (const float*)d_in[11];
    const float* dtw  = (const float*)d_in[12];
    const float* dtb  = (const float*)d_in[13];
    const float* alog = (const float*)d_in[14];
    const float* dvec = (const float*)d_in[15];
    const float* ow   = (const float*)d_in[16];

    float* ws = (float*)d_ws;
    unsigned short* xn    = (unsigned short*)(ws);             // 1,572,864 f
    unsigned short* xz    = (unsigned short*)(ws + 1572864);   // 6,291,456 f
    unsigned short* xc    = (unsigned short*)(ws + 7864320);   // 6,291,456 f
    unsigned short* dty   = (unsigned short*)(ws + 14155776);  // 6,291,456 f
    float*          bcb   = ws + 20447232;                     // 1,572,864 f
    float*          st1   = ws + 22020096;                     // 4,194,304 f (8*NCH*128*16)
    float*          hst   = ws + 26214400;                     // 2,097,152 f (8*NCH*128*8)
    unsigned short* wallb = (unsigned short*)(ws + 28311552);  //    36,864 f
    unsigned short* wib   = (unsigned short*)(ws + 28348416);  //    32,768 f
    unsigned short* owb   = (unsigned short*)(ws + 28381184);  //    16,384 f
    float*          lam   = ws + 28397568;                     //         1

    k_lam   <<<1, 64, 0, stream>>>(lq, lam);
    k_wall  <<<dim3(4,144), 128, 0, stream>>>(dtw, xpw, wallb);
    k_prep  <<<96, 256, 0, stream>>>(wi, ow, wib, owb);
    k_normT <<<384, 256, 0, stream>>>(x, n1w, n1b, xn);
    k_inproj<<<dim3(192, 4), 256, 0, stream>>>(xn, wib, xz);
    k_conv  <<<2*NB*(LSEQ/64), 256, 0, stream>>>(xz, cw, cb, xc);
    k_xproj <<<dim3(96, 8), 256, 0, stream>>>(xc, wallb, dtb, dty, bcb);
    k_scan1 <<<8*NCH, 128, 0, stream>>>(dty, xc, bcb, alog, st1);
    k_scan2 <<<32, 256, 0, stream>>>(st1, hst);
    k_scan3 <<<8*NCH, 128, 0, stream>>>(dty, xc, bcb, xz, hst, alog, dvec);
    k_final <<<dim3(192, 2), 256, 0, stream>>>(dty, owb, x, lam, slw, slb, n2w, n2b, (float*)d_out);
}

// Round 8
// 283.088 us; speedup vs baseline: 4.1093x; 1.0538x over previous
//
#include <hip/hip_runtime.h>
#include <math.h>

#define DIMC 128
#define LSEQ 12288
#define NB 2
#define BLR 24576   // NB*LSEQ
#define EPSV 1e-5f
#define NCH 256     // scan chunks per row
#define LC 48       // chunk length (NCH*LC = LSEQ)
#define KP 132      // LDS row pad (ushorts) for MFMA staging

typedef __bf16 bf16x8 __attribute__((ext_vector_type(8)));
typedef __attribute__((ext_vector_type(4))) float f4_t;

__device__ __forceinline__ float sigf(float x){ return 1.f/(1.f+__expf(-x)); }
// cheap softplus: log1pf (libm, branchy) -> v_exp + v_log.  bf16-grade accuracy.
__device__ __forceinline__ float softplusf(float x){
    return fmaxf(x,0.f) + __logf(1.f + __expf(-fabsf(x)));
}
__device__ __forceinline__ float bf2f(unsigned short u){
    union { unsigned int i; float f; } v; v.i = ((unsigned int)u) << 16; return v.f;
}
__device__ __forceinline__ unsigned short f2bf(float f){
    union { float f; unsigned int i; } v; v.f = f;
    unsigned int b = v.i + 0x7FFFu + ((v.i >> 16) & 1u);
    return (unsigned short)(b >> 16);
}
__device__ __forceinline__ bf16x8 ld_frag8(const unsigned short* p){   // 8B-aligned LDS
    union { uint2 u[2]; bf16x8 v; } r;
    r.u[0] = *(const uint2*)(p);
    r.u[1] = *(const uint2*)(p+4);
    return r.v;
}
__device__ __forceinline__ bf16x8 ld_frag16g(const unsigned short* p){ // 16B-aligned global
    union { uint4 u; bf16x8 v; } r; r.u = *(const uint4*)p; return r.v;
}

// ---------------------------------------------------------------- lam = sigmoid(sum(lambda_q))
__global__ void k_lam(const float* __restrict__ lq, float* __restrict__ lam){
    int lane = threadIdx.x;
    float v = lq[lane] + lq[lane+64];
    for (int m = 32; m; m >>= 1) v += __shfl_xor(v, m);
    if (lane == 0) *lam = 1.f/(1.f+__expf(-v));
}

// ---------------------------------------------------------------- W_all[inst][144][128] (bf16)
__global__ void k_wall(const float* __restrict__ dtw, const float* __restrict__ xpw,
                       unsigned short* __restrict__ wallb){
    int inst = blockIdx.x, j = blockIdx.y, k = threadIdx.x;  // grid (4,144), block 128
    const float* xp = xpw + (size_t)inst*24*128;
    float v;
    if (j < 128){
        const float* dw = dtw + (size_t)inst*128*8 + (size_t)j*8;
        v = 0.f;
        #pragma unroll
        for (int r = 0; r < 8; r++) v += dw[r]*xp[r*128 + k];
    } else {
        v = xp[(8 + (j-128))*128 + k];
    }
    wallb[((size_t)inst*144 + j)*128 + k] = f2bf(v);
}

// ---------------------------------------------------------------- wi, ow -> bf16
__global__ __launch_bounds__(256) void k_prep(const float* __restrict__ wi, const float* __restrict__ ow,
    unsigned short* __restrict__ wib, unsigned short* __restrict__ owb){
    int idx = (blockIdx.x*256 + threadIdx.x)*4;   // grid 96 -> 98304 elems
    const float* src; unsigned short* dst; int off;
    if (idx < 65536){ src = wi;  dst = wib; off = idx; }
    else            { src = ow;  dst = owb; off = idx - 65536; }
    float4 v = *(const float4*)&src[off];
    ushort4 o; o.x=f2bf(v.x); o.y=f2bf(v.y); o.z=f2bf(v.z); o.w=f2bf(v.w);
    *(ushort4*)&dst[off] = o;
}

// ---------------------------------------------------------------- LN1 (stats fused) + transpose -> xn bf16 [b*l][128]
__global__ __launch_bounds__(256) void k_normT(const float* __restrict__ x,
    const float* __restrict__ w1, const float* __restrict__ b1, unsigned short* __restrict__ xn)
{
    __shared__ float t[64*129];
    __shared__ float red1[256], red2[256];
    __shared__ float stt[128];
    const int bb = blockIdx.x / 192;
    const int l0 = (blockIdx.x % 192) * 64;
    const int tid = threadIdx.x;
    const int li = tid & 63, cg = tid >> 6;
    #pragma unroll
    for (int p = 0; p < 32; p++){
        int c = p*4 + cg;
        t[li*129 + c] = x[(size_t)bb*DIMC*LSEQ + (size_t)c*LSEQ + l0 + li];
    }
    __syncthreads();
    {
        int r = tid >> 2, qg = tid & 3;
        float s = 0.f, s2 = 0.f;
        #pragma unroll
        for (int j = 0; j < 32; j++){ float v = t[r*129 + qg*32 + j]; s += v; s2 += v*v; }
        red1[qg*64 + r] = s; red2[qg*64 + r] = s2;
    }
    __syncthreads();
    if (tid < 64){
        float s = 0.f, s2 = 0.f;
        #pragma unroll
        for (int g = 0; g < 4; g++){ s += red1[g*64 + tid]; s2 += red2[g*64 + tid]; }
        float mu = s*(1.f/128.f);
        float var = s2*(1.f/128.f) - mu*mu;
        stt[tid*2] = mu; stt[tid*2+1] = rsqrtf(var + EPSV);
    }
    __syncthreads();
    const int c2 = (tid & 63)*2, lg = tid >> 6;
    #pragma unroll
    for (int p = 0; p < 16; p++){
        int l = p*4 + lg;
        float mu = stt[l*2], rs = stt[l*2+1];
        float v0 = (t[l*129 + c2    ] - mu)*rs*w1[c2    ] + b1[c2    ];
        float v1 = (t[l*129 + c2 + 1] - mu)*rs*w1[c2 + 1] + b1[c2 + 1];
        unsigned int o = (unsigned int)f2bf(v0) | ((unsigned int)f2bf(v1) << 16);
        *(unsigned int*)&xn[(size_t)(bb*LSEQ + l0 + l)*DIMC + c2] = o;
    }
}

// ---------------------------------------------------------------- in_proj MFMA: [128m x 128n x 128k] tiles
// LDS 33.8 KB -> 4 blocks/CU; launch_bounds(256,4) = 16 waves/CU
__global__ __launch_bounds__(256,4) void k_inproj(const unsigned short* __restrict__ xn,
    const unsigned short* __restrict__ wib, unsigned short* __restrict__ xz)
{
    __shared__ __align__(16) unsigned short As[128*KP];   // 33792 B
    const int row0 = blockIdx.x * 128;   // grid.x = 192
    const int j0   = blockIdx.y * 128;   // grid.y = 4
    const int tid = threadIdx.x;
    #pragma unroll
    for (int p = 0; p < 8; p++){
        int idx = p*256 + tid; int li = idx >> 4; int g = (idx & 15)*8;
        uint4 va = *(const uint4*)&xn[(size_t)(row0+li)*DIMC + g];
        *(uint2*)&As[li*KP + g]     = make_uint2(va.x, va.y);
        *(uint2*)&As[li*KP + g + 4] = make_uint2(va.z, va.w);
    }
    __syncthreads();
    const int lane = tid & 63, w = tid >> 6;
    const int m15 = lane & 15, q = lane >> 4;
    f4_t zf = {0.f,0.f,0.f,0.f};
    f4_t acc[2][8];
    #pragma unroll
    for (int i = 0; i < 2; i++)
        #pragma unroll
        for (int j = 0; j < 8; j++) acc[i][j] = zf;
    #pragma unroll
    for (int ks = 0; ks < 4; ks++){
        int k0 = ks*32 + q*8;
        bf16x8 a0 = ld_frag8(&As[(w*32      + m15)*KP + k0]);
        bf16x8 a1 = ld_frag8(&As[(w*32 + 16 + m15)*KP + k0]);
        #pragma unroll
        for (int nt = 0; nt < 8; nt++){
            bf16x8 b = ld_frag16g(&wib[(size_t)(j0 + nt*16 + m15)*DIMC + k0]);
            acc[0][nt] = __builtin_amdgcn_mfma_f32_16x16x32_bf16(a0, b, acc[0][nt], 0,0,0);
            acc[1][nt] = __builtin_amdgcn_mfma_f32_16x16x32_bf16(a1, b, acc[1][nt], 0,0,0);
        }
    }
    __syncthreads();
    unsigned short* ep = As;             // reuse
    #pragma unroll
    for (int mi = 0; mi < 2; mi++)
        #pragma unroll
        for (int nt = 0; nt < 8; nt++){
            int row = w*32 + mi*16 + q*4;
            int col = nt*16 + m15;
            #pragma unroll
            for (int i = 0; i < 4; i++)
                ep[(row+i)*KP + col] = f2bf(acc[mi][nt][i]);
        }
    __syncthreads();
    #pragma unroll
    for (int p = 0; p < 8; p++){
        int idx = p*256 + tid; int li = idx >> 4; int g = (idx & 15)*8;
        uint2 u0 = *(const uint2*)&ep[li*KP + g];
        uint2 u1 = *(const uint2*)&ep[li*KP + g + 4];
        uint4 o; o.x=u0.x; o.y=u0.y; o.z=u1.x; o.w=u1.y;
        *(uint4*)&xz[(size_t)(row0+li)*512 + j0 + g] = o;
    }
}

// ---------------------------------------------------------------- conv (both directions) + silu
__global__ __launch_bounds__(256) void k_conv(const unsigned short* __restrict__ xz,
    const float* __restrict__ cw, const float* __restrict__ cb, unsigned short* __restrict__ xc)
{
    __shared__ unsigned short tile[70][144];
    const int bid = blockIdx.x;                // grid = 2*2*192
    const int lt = bid % 192;
    const int bb = (bid/192) % NB;
    const int m  = bid / (192*NB);
    const int l0 = lt * 64;
    const int tid = threadIdx.x;
    for (int idx = tid; idx < 70*16; idx += 256){
        int r = idx >> 4, cq = idx & 15;
        int l = l0 - 3 + r;
        uint4 v = make_uint4(0,0,0,0);
        if (l >= 0 && l < LSEQ)
            v = *(const uint4*)&xz[((size_t)(bb*LSEQ + l))*512 + m*256 + cq*8];
        *(uint4*)&tile[r][cq*8] = v;
    }
    __syncthreads();
    const int dimi = tid & 127, lg = tid >> 7;
    float w0a[4], w1a[4];
    #pragma unroll
    for (int k = 0; k < 4; k++){
        w0a[k] = cw[((size_t)(m*2+0)*DIMC + dimi)*4 + k];
        w1a[k] = cw[((size_t)(m*2+1)*DIMC + dimi)*4 + k];
    }
    const float b0 = cb[(m*2+0)*DIMC + dimi];
    const float b1v = cb[(m*2+1)*DIMC + dimi];
    for (int p = 0; p < 32; p++){
        int li = p*2 + lg;
        float t0 = bf2f(tile[li  ][dimi]);
        float t1 = bf2f(tile[li+1][dimi]);
        float t2 = bf2f(tile[li+2][dimi]);
        float t3 = bf2f(tile[li+3][dimi]);
        float t4 = bf2f(tile[li+4][dimi]);
        float t5 = bf2f(tile[li+5][dimi]);
        float t6 = bf2f(tile[li+6][dimi]);
        float v0 = b0  + w0a[0]*t0 + w0a[1]*t1 + w0a[2]*t2 + w0a[3]*t3;
        float v1 = b1v + w1a[3]*t3 + w1a[2]*t4 + w1a[1]*t5 + w1a[0]*t6;
        v0 = v0 * sigf(v0);
        v1 = v1 * sigf(v1);
        xc[(((size_t)(m*2+0)*NB + bb)*LSEQ + l0 + li)*DIMC + dimi] = f2bf(v0);
        xc[(((size_t)(m*2+1)*NB + bb)*LSEQ + l0 + li)*DIMC + dimi] = f2bf(v1);
    }
}

// ---------------------------------------------------------------- x_proj MFMA: [128m x 144n x 128k] per ib
// bq removed (bc stored direct from fragments) -> LDS 33.8 KB -> 4 blocks/CU
__global__ __launch_bounds__(256,4) void k_xproj(const unsigned short* __restrict__ xc,
    const unsigned short* __restrict__ wallb, const float* __restrict__ dtb,
    unsigned short* __restrict__ dty, float* __restrict__ bcb)
{
    __shared__ __align__(16) unsigned short As[128*KP];   // 33792 B
    const int row0 = blockIdx.x * 128;   // grid.x = 96
    const int ib   = blockIdx.y;         // 0..7
    const int inst = ib >> 1;
    const int tid = threadIdx.x;
    const size_t abase = (size_t)ib * LSEQ * DIMC;
    #pragma unroll
    for (int p = 0; p < 8; p++){
        int idx = p*256 + tid; int li = idx >> 4; int g = (idx & 15)*8;
        uint4 va = *(const uint4*)&xc[abase + (size_t)(row0+li)*DIMC + g];
        *(uint2*)&As[li*KP + g]     = make_uint2(va.x, va.y);
        *(uint2*)&As[li*KP + g + 4] = make_uint2(va.z, va.w);
    }
    __syncthreads();
    const int lane = tid & 63, w = tid >> 6;
    const int m15 = lane & 15, q = lane >> 4;
    f4_t zf = {0.f,0.f,0.f,0.f};
    f4_t acc[2][9];
    #pragma unroll
    for (int i = 0; i < 2; i++)
        #pragma unroll
        for (int j = 0; j < 9; j++) acc[i][j] = zf;
    #pragma unroll
    for (int ks = 0; ks < 4; ks++){
        int k0 = ks*32 + q*8;
        bf16x8 a0 = ld_frag8(&As[(w*32      + m15)*KP + k0]);
        bf16x8 a1 = ld_frag8(&As[(w*32 + 16 + m15)*KP + k0]);
        #pragma unroll
        for (int nt = 0; nt < 9; nt++){
            bf16x8 b = ld_frag16g(&wallb[((size_t)inst*144 + nt*16 + m15)*DIMC + k0]);
            acc[0][nt] = __builtin_amdgcn_mfma_f32_16x16x32_bf16(a0, b, acc[0][nt], 0,0,0);
            acc[1][nt] = __builtin_amdgcn_mfma_f32_16x16x32_bf16(a1, b, acc[1][nt], 0,0,0);
        }
    }
    // bc: store direct from fragments (col 128+m15) — 64B coalesced segments per quad
    #pragma unroll
    for (int mi = 0; mi < 2; mi++){
        int row = w*32 + mi*16 + q*4;
        #pragma unroll
        for (int i = 0; i < 4; i++)
            bcb[((size_t)ib*LSEQ + row0 + row + i)*16 + m15] = acc[mi][8][i];
    }
    __syncthreads();
    unsigned short* ep = As;             // dt bf16 [128][KP]
    #pragma unroll
    for (int nt = 0; nt < 8; nt++){
        int col = nt*16 + m15;
        float bias = dtb[inst*DIMC + col];
        #pragma unroll
        for (int mi = 0; mi < 2; mi++){
            int row = w*32 + mi*16 + q*4;
            #pragma unroll
            for (int i = 0; i < 4; i++)
                ep[(row+i)*KP + col] = f2bf(softplusf(acc[mi][nt][i] + bias));
        }
    }
    __syncthreads();
    #pragma unroll
    for (int p = 0; p < 8; p++){
        int idx = p*256 + tid; int li = idx >> 4; int g = (idx & 15)*8;
        uint2 u0 = *(const uint2*)&ep[li*KP + g];
        uint2 u1 = *(const uint2*)&ep[li*KP + g + 4];
        uint4 o; o.x=u0.x; o.y=u0.y; o.z=u1.x; o.w=u1.y;
        *(uint4*)&dty[abase + (size_t)(row0+li)*DIMC + g] = o;
    }
}

// ---------------------------------------------------------------- scan S1 (per-chunk reduce)
__global__ __launch_bounds__(128) void k_scan1(const unsigned short* __restrict__ dt,
    const unsigned short* __restrict__ xc, const float* __restrict__ bcb,
    const float* __restrict__ alog, float* __restrict__ st)
{
    const int ib = blockIdx.x & 7;
    const int c  = blockIdx.x >> 3;            // 0..NCH-1
    const int inst = ib >> 1;
    const int d = inst & 1;
    const int tid = threadIdx.x;
    float Av[8];
    #pragma unroll
    for (int n = 0; n < 8; n++) Av[n] = -__expf(alog[((size_t)inst*DIMC + tid)*8 + n]);
    const size_t rbase = (size_t)ib*LSEQ*DIMC;
    float Ac[8], Bc[8];
    #pragma unroll
    for (int n = 0; n < 8; n++){ Ac[n] = 1.f; Bc[n] = 0.f; }
    #pragma unroll 4
    for (int s = 0; s < LC; s++){
        int j = c*LC + s;
        int l = d ? (LSEQ-1-j) : j;
        size_t ro = rbase + (size_t)l*DIMC + tid;
        float dtv = bf2f(dt[ro]);
        float uv  = bf2f(xc[ro]);
        const float* bp = bcb + ((size_t)ib*LSEQ + l)*16;
        float4 bA = *(const float4*)bp;
        float4 bB = *(const float4*)(bp+4);
        float bv[8] = {bA.x,bA.y,bA.z,bA.w,bB.x,bB.y,bB.z,bB.w};
        float du = dtv*uv;
        #pragma unroll
        for (int n = 0; n < 8; n++){
            float a = __expf(dtv*Av[n]);
            Bc[n] = a*Bc[n] + du*bv[n];
            Ac[n] *= a;
        }
    }
    float* so = st + (((size_t)ib*NCH + c)*DIMC + tid)*16;
    #pragma unroll
    for (int n = 0; n < 8; n++){ so[n] = Ac[n]; so[8+n] = Bc[n]; }
}

// ---------------------------------------------------------------- scan S2 (cross-chunk exclusive prefix)
__global__ __launch_bounds__(256) void k_scan2(const float* __restrict__ st, float* __restrict__ hst){
    int gid = blockIdx.x*256 + threadIdx.x;    // 8192 threads
    int ib = gid >> 10;
    int r  = gid & 1023;
    int dim = r >> 3, n = r & 7;
    float Bp = 0.f;
    for (int c = 0; c < NCH; c++){
        size_t o = (((size_t)ib*NCH + c)*DIMC + dim)*16;
        float A = st[o+n], Bv = st[o+8+n];
        hst[(((size_t)ib*NCH + c)*DIMC + dim)*8 + n] = Bp;
        Bp = A*Bp + Bv;
    }
}

// ---------------------------------------------------------------- scan S3 (replay, y in place over dt)
__global__ __launch_bounds__(128) void k_scan3(unsigned short* __restrict__ dty,
    const unsigned short* __restrict__ xc, const float* __restrict__ bcb,
    const unsigned short* __restrict__ xz, const float* __restrict__ hst,
    const float* __restrict__ alog, const float* __restrict__ dvec)
{
    const int ib = blockIdx.x & 7;
    const int c  = blockIdx.x >> 3;
    const int inst = ib >> 1, bb = ib & 1;
    const int m = inst >> 1, d = inst & 1;
    const int tid = threadIdx.x;
    float Av[8];
    #pragma unroll
    for (int n = 0; n < 8; n++) Av[n] = -__expf(alog[((size_t)inst*DIMC + tid)*8 + n]);
    const float Dv = dvec[inst*DIMC + tid];
    float h[8];
    #pragma unroll
    for (int n = 0; n < 8; n++) h[n] = hst[(((size_t)ib*NCH + c)*DIMC + tid)*8 + n];
    const size_t rbase = (size_t)ib*LSEQ*DIMC;
    const size_t zbase = (size_t)bb*LSEQ*512 + m*256 + 128;
    #pragma unroll 2
    for (int s = 0; s < LC; s++){
        int j = c*LC + s;
        int l = d ? (LSEQ-1-j) : j;
        size_t ro = rbase + (size_t)l*DIMC + tid;
        float dtv = bf2f(dty[ro]);
        float uv  = bf2f(xc[ro]);
        const float* bp = bcb + ((size_t)ib*LSEQ + l)*16;
        float4 bA = *(const float4*)bp;
        float4 bB = *(const float4*)(bp+4);
        float4 cA = *(const float4*)(bp+8);
        float4 cB = *(const float4*)(bp+12);
        float bv[8] = {bA.x,bA.y,bA.z,bA.w,bB.x,bB.y,bB.z,bB.w};
        float cv[8] = {cA.x,cA.y,cA.z,cA.w,cB.x,cB.y,cB.z,cB.w};
        float du = dtv*uv;
        float y = uv*Dv;
        #pragma unroll
        for (int n = 0; n < 8; n++){
            float a = __expf(dtv*Av[n]);
            h[n] = a*h[n] + du*bv[n];
            y += h[n]*cv[n];
        }
        float zv = bf2f(xz[zbase + (size_t)l*512 + tid]);
        y *= zv * sigf(zv);
        dty[ro] = f2bf(y);
    }
}

// ---------------------------------------------------------------- out_proj MFMA + diff + LN + add x + LN + T-store
// LDS 52.5 KB -> 3 blocks/CU
__global__ __launch_bounds__(256,3) void k_final(const unsigned short* __restrict__ y,
    const unsigned short* __restrict__ owb, const float* __restrict__ x, const float* __restrict__ lamp,
    const float* __restrict__ sw, const float* __restrict__ sb,
    const float* __restrict__ n2w, const float* __restrict__ n2b, float* __restrict__ outp)
{
    __shared__ __align__(16) char smem[52480];
    unsigned short* Ast = (unsigned short*)smem;             // phase 1: [2*64][KP] = 33792 B
    float* yt            = (float*)smem;                     // phase 2: [64][129] f32 = 33024 B
    unsigned short* xtb  = (unsigned short*)(smem + 33024);  // [64][132] bf16 = 16896 B
    float* red1          = (float*)(smem + 49920);           // 1024 B
    float* red2          = (float*)(smem + 50944);           // 1024 B
    float* stt           = (float*)(smem + 51968);           //  512 B
    const int bb = blockIdx.y;
    const int l0 = blockIdx.x * 64;                  // grid.x = 192
    const int tid = threadIdx.x;
    const float lam = *lamp;
    #pragma unroll
    for (int p = 0; p < 8; p++){
        int idx = p*256 + tid; int mm = idx >> 10; int li = (idx >> 4) & 63; int g = (idx & 15)*8;
        uint4 vf = *(const uint4*)&y[(((size_t)(mm*2+0)*NB + bb)*LSEQ + l0 + li)*DIMC + g];
        uint4 vb = *(const uint4*)&y[(((size_t)(mm*2+1)*NB + bb)*LSEQ + l0 + li)*DIMC + g];
        const unsigned short* uf = (const unsigned short*)&vf;
        const unsigned short* ub = (const unsigned short*)&vb;
        unsigned short o[8];
        #pragma unroll
        for (int j = 0; j < 8; j++) o[j] = f2bf(bf2f(uf[j]) + bf2f(ub[j]));
        *(uint2*)&Ast[(mm*64 + li)*KP + g]     = *(uint2*)&o[0];
        *(uint2*)&Ast[(mm*64 + li)*KP + g + 4] = *(uint2*)&o[4];
    }
    __syncthreads();
    const int lane = tid & 63, w = tid >> 6;
    const int m15 = lane & 15, q = lane >> 4;
    f4_t zf = {0.f,0.f,0.f,0.f};
    f4_t acc[2][8];
    #pragma unroll
    for (int i = 0; i < 2; i++)
        #pragma unroll
        for (int j = 0; j < 8; j++) acc[i][j] = zf;
    #pragma unroll
    for (int ks = 0; ks < 4; ks++){
        int k0 = ks*32 + q*8;
        bf16x8 a0 = ld_frag8(&Ast[(       w*16 + m15)*KP + k0]);
        bf16x8 a1 = ld_frag8(&Ast[(64   + w*16 + m15)*KP + k0]);
        #pragma unroll
        for (int nt = 0; nt < 8; nt++){
            bf16x8 b0 = ld_frag16g(&owb[((size_t)0*DIMC + nt*16 + m15)*DIMC + k0]);
            bf16x8 b1 = ld_frag16g(&owb[((size_t)1*DIMC + nt*16 + m15)*DIMC + k0]);
            acc[0][nt] = __builtin_amdgcn_mfma_f32_16x16x32_bf16(a0, b0, acc[0][nt], 0,0,0);
            acc[1][nt] = __builtin_amdgcn_mfma_f32_16x16x32_bf16(a1, b1, acc[1][nt], 0,0,0);
        }
    }
    __syncthreads();                                 // Ast dead; epilogue overlays
    #pragma unroll
    for (int nt = 0; nt < 8; nt++){
        int row = w*16 + q*4;
        int col = nt*16 + m15;
        #pragma unroll
        for (int i = 0; i < 4; i++)
            yt[(row+i)*129 + col] = acc[0][nt][i] - lam*acc[1][nt][i];
    }
    {
        const int li = tid & 63, cg = tid >> 6;
        #pragma unroll
        for (int p = 0; p < 32; p++){
            int c = p*4 + cg;
            xtb[li*132 + c] = f2bf(x[(size_t)bb*DIMC*LSEQ + (size_t)c*LSEQ + l0 + li]);
        }
    }
    __syncthreads();
    const int r = tid & 63, g = tid >> 6;            // 4 groups of 32 cols
    float s = 0.f, s2 = 0.f;
    #pragma unroll
    for (int k = 0; k < 32; k++){ float v = yt[r*129 + g*32 + k]; s += v; s2 += v*v; }
    red1[g*64 + r] = s; red2[g*64 + r] = s2;
    __syncthreads();
    if (tid < 64){
        float ss = 0.f, ss2 = 0.f;
        #pragma unroll
        for (int gg = 0; gg < 4; gg++){ ss += red1[gg*64 + tid]; ss2 += red2[gg*64 + tid]; }
        float mu = ss*(1.f/128.f);
        float var = ss2*(1.f/128.f) - mu*mu;
        stt[tid*2] = mu; stt[tid*2+1] = rsqrtf(var + EPSV);
    }
    __syncthreads();
    float mu1 = stt[r*2], rs1 = stt[r*2+1];
    s = 0.f; s2 = 0.f;
    #pragma unroll
    for (int k = 0; k < 32; k++){
        int c = g*32 + k;
        float v = (yt[r*129+c] - mu1)*rs1*sw[c] + sb[c] + bf2f(xtb[r*132+c]);
        yt[r*129+c] = v;
        s += v; s2 += v*v;
    }
    __syncthreads();
    red1[g*64 + r] = s; red2[g*64 + r] = s2;
    __syncthreads();
    if (tid < 64){
        float ss = 0.f, ss2 = 0.f;
        #pragma unroll
        for (int gg = 0; gg < 4; gg++){ ss += red1[gg*64 + tid]; ss2 += red2[gg*64 + tid]; }
        float mu = ss*(1.f/128.f);
        float var = ss2*(1.f/128.f) - mu*mu;
        stt[tid*2] = mu; stt[tid*2+1] = rsqrtf(var + EPSV);
    }
    __syncthreads();
    float mu2 = stt[r*2], rs2 = stt[r*2+1];
    #pragma unroll
    for (int k = 0; k < 32; k++){
        int c = g*32 + k;
        float o = (yt[r*129+c] - mu2)*rs2*n2w[c] + n2b[c];
        outp[(size_t)bb*DIMC*LSEQ + (size_t)c*LSEQ + l0 + r] = o;
    }
}

// ----------------------------------------------------------------
extern "C" void kernel_launch(void* const* d_in, const int* in_sizes, int n_in,
                              void* d_out, int out_size, void* d_ws, size_t ws_size,
                              hipStream_t stream)
{
    const float* x    = (const float*)d_in[0];
    const float* n1w  = (const float*)d_in[1];
    const float* n1b  = (const float*)d_in[2];
    const float* n2w  = (const float*)d_in[3];
    const float* n2b  = (const float*)d_in[4];
    const float* slw  = (const float*)d_in[5];
    const float* slb  = (const float*)d_in[6];
    const float* lq   = (const float*)d_in[7];
    const float* wi   = (const float*)d_in[8];
    const float* cw   = (const float*)d_in[9];
    const float* cb   = (const float*)d_in[10];
    const float* xpw  = (const float*)d_in[11];
    const float* dtw  = (const float*)d_in[12];
    const float* dtb  = (const float*)d_in[13];
    const float* alog = (const float*)d_in[14];
    const float* dvec = (const float*)d_in[15];
    const float* ow   = (const float*)d_in[16];

    float* ws = (float*)d_ws;
    unsigned short* xn    = (unsigned short*)(ws);             // 1,572,864 f
    unsigned short* xz    = (unsigned short*)(ws + 1572864);   // 6,291,456 f
    unsigned short* xc    = (unsigned short*)(ws + 7864320);   // 6,291,456 f
    unsigned short* dty   = (unsigned short*)(ws + 14155776);  // 6,291,456 f
    float*          bcb   = ws + 20447232;                     // 1,572,864 f
    float*          st1   = ws + 22020096;                     // 4,194,304 f (8*NCH*128*16)
    float*          hst   = ws + 26214400;                     // 2,097,152 f (8*NCH*128*8)
    unsigned short* wallb = (unsigned short*)(ws + 28311552);  //    36,864 f
    unsigned short* wib   = (unsigned short*)(ws + 28348416);  //    32,768 f
    unsigned short* owb   = (unsigned short*)(ws + 28381184);  //    16,384 f
    float*          lam   = ws + 28397568;                     //         1

    k_lam   <<<1, 64, 0, stream>>>(lq, lam);
    k_wall  <<<dim3(4,144), 128, 0, stream>>>(dtw, xpw, wallb);
    k_prep  <<<96, 256, 0, stream>>>(wi, ow, wib, owb);
    k_normT <<<384, 256, 0, stream>>>(x, n1w, n1b, xn);
    k_inproj<<<dim3(192, 4), 256, 0, stream>>>(xn, wib, xz);
    k_conv  <<<2*NB*(LSEQ/64), 256, 0, stream>>>(xz, cw, cb, xc);
    k_xproj <<<dim3(96, 8), 256, 0, stream>>>(xc, wallb, dtb, dty, bcb);
    k_scan1 <<<8*NCH, 128, 0, stream>>>(dty, xc, bcb, alog, st1);
    k_scan2 <<<32, 256, 0, stream>>>(st1, hst);
    k_scan3 <<<8*NCH, 128, 0, stream>>>(dty, xc, bcb, xz, hst, alog, dvec);
    k_final <<<dim3(192, 2), 256, 0, stream>>>(dty, owb, x, lam, slw, slb, n2w, n2b, (float*)d_out);
}